// Round 7
// baseline (209.974 us; speedup 1.0000x reference)
//
#include <hip/hip_runtime.h>
#include <hip/hip_bf16.h>

typedef unsigned short u16;
typedef __attribute__((ext_vector_type(8))) __bf16 bf8v;
typedef __attribute__((ext_vector_type(8))) _Float16 f16x8;
typedef __attribute__((ext_vector_type(2))) _Float16 h2v;
typedef __attribute__((ext_vector_type(4))) float f32x4;
typedef __attribute__((ext_vector_type(4))) unsigned uint4v;

#define B_ 4
#define N_ 16384
#define M_ 16384
#define K_ 16
#define C_ 64
#define O_ 64
#define G_ 8

__device__ __forceinline__ float bf2f(u16 x){
  union { unsigned u; float f; } v; v.u = ((unsigned)x) << 16; return v.f;
}
__device__ __forceinline__ u16 f2bf(float f){
  union { float f; unsigned u; } v; v.f = f;
  unsigned u = v.u;
  return (u16)((u + 0x7FFFu + ((u >> 16) & 1u)) >> 16);
}
__device__ __forceinline__ u16 f2h(float f){
  union { _Float16 h; u16 u; } v; v.h = (_Float16)f; return v.u;
}
__device__ __forceinline__ h2v mkh2(float a, float b){
  h2v r = {(_Float16)a, (_Float16)b}; return r;
}

// ---------------------------------------------------------------------------
// pre_kernel (round-2/3 version, best measured residue): blocks [0,256) KV
// (+pos4 pack), [256,512) QC (+cp4 pack, inline Bw setup).  256 points/block.
// ---------------------------------------------------------------------------
__global__ __launch_bounds__(256) void pre_kernel(
    const float* __restrict__ center_pos, const float* __restrict__ center_fea,
    const float* __restrict__ pos, const float* __restrict__ fea,
    const float* __restrict__ Wq, const float* __restrict__ bq,
    const float* __restrict__ Wk, const float* __restrict__ bk,
    const float* __restrict__ Wv, const float* __restrict__ bv,
    const float* __restrict__ cpe_w1, const float* __restrict__ cpe_s, const float* __restrict__ cpe_b,
    const float* __restrict__ cpe_w2, const float* __restrict__ cpe_b2,
    const float* __restrict__ we_w1,
    u16* __restrict__ xk, u16* __restrict__ xv, float* __restrict__ qw,
    float* __restrict__ pos4, float* __restrict__ cp4)
{
  __shared__ u16 sWT[128*72];
  __shared__ u16 sA[64*72];
  __shared__ u16 sOut[64*136];
  __shared__ float sMisc[256];
  __shared__ float sCi[8];
  int tid = threadIdx.x;
  int l = tid & 63, w = tid >> 6, c = l & 15, q = l >> 4;
  int blk = blockIdx.x;

  if (blk < 256){
    int P0 = blk * 256; int b = P0 >> 14; int n00 = P0 & (N_-1);
    const float* fb = fea + (long)b*C_*N_;
    for (int e = tid; e < 8192; e += 256){
      int k = e >> 7, col = e & 127;
      float v = (col < 64) ? Wk[k*64 + col] : Wv[k*64 + (col-64)];
      sWT[col*72 + k] = f2bf(v);
    }
    if (tid < 128) sMisc[tid] = (tid < 64) ? bk[tid] : bv[tid-64];
    {
      long pg = (long)P0 + tid;
      f32x4 r = {pos[pg*3], pos[pg*3+1], pos[pg*3+2], 0.f};
      ((f32x4*)pos4)[pg] = r;
    }

    #pragma unroll 1
    for (int s = 0; s < 4; s++){
      int n0 = n00 + s*64;
      #pragma unroll
      for (int pp = 0; pp < 4; pp++){
        int k = pp*16 + (tid >> 4);
        int nf = (tid & 15)*4;
        f32x4 v = *(const f32x4*)&fb[(long)k*N_ + n0 + nf];
        sA[(nf+0)*72+k] = f2bf(v[0]); sA[(nf+1)*72+k] = f2bf(v[1]);
        sA[(nf+2)*72+k] = f2bf(v[2]); sA[(nf+3)*72+k] = f2bf(v[3]);
      }
      __syncthreads();

      bf8v af0 = *(const bf8v*)&sA[(w*16+c)*72 + q*8];
      bf8v af1 = *(const bf8v*)&sA[(w*16+c)*72 + 32 + q*8];
      f32x4 acc[8];
      #pragma unroll
      for (int t = 0; t < 8; t++){
        float bb = sMisc[16*t + c];
        f32x4 a_ = {bb, bb, bb, bb};
        bf8v b0 = *(const bf8v*)&sWT[(16*t + c)*72 + q*8];
        bf8v b1 = *(const bf8v*)&sWT[(16*t + c)*72 + 32 + q*8];
        a_ = __builtin_amdgcn_mfma_f32_16x16x32_bf16(af0, b0, a_, 0,0,0);
        a_ = __builtin_amdgcn_mfma_f32_16x16x32_bf16(af1, b1, a_, 0,0,0);
        acc[t] = a_;
      }
      #pragma unroll
      for (int t = 0; t < 8; t++)
        #pragma unroll
        for (int r = 0; r < 4; r++)
          sOut[(w*16 + q*4 + r)*136 + 16*t + c] = f2bf(acc[t][r]);
      __syncthreads();

      #pragma unroll
      for (int rep = 0; rep < 4; rep++){
        int chunk = rep*256 + tid;
        int pt = chunk >> 4, c8i = chunk & 15;
        uint4v val = *(const uint4v*)&sOut[pt*136 + c8i*8];
        int col8 = c8i*8;
        long row = (long)P0 + s*64 + pt;
        if (col8 < 64) *(uint4v*)(xk + row*64 + col8)      = val;
        else           *(uint4v*)(xv + row*64 + (col8-64)) = val;
      }
      __syncthreads();
    }
  } else {
    int P0 = (blk - 256) * 256; int b = P0 >> 14; int m00 = P0 & (M_-1);
    const float* cfb = center_fea + (long)b*C_*M_;
    float* sWe = (float*)sOut;
    float* sQ  = (float*)sOut;
    for (int e = tid; e < 512; e += 256) sWe[e] = we_w1[e];
    if (tid < 64){
      float sc = cpe_s[tid];
      sMisc[tid]     = cpe_w1[tid]*sc;
      sMisc[64+tid]  = cpe_w1[64+tid]*sc;
      sMisc[128+tid] = cpe_w1[128+tid]*sc;
      sMisc[192+tid] = cpe_b[tid];
    }
    {
      long pg = (long)P0 + tid;
      f32x4 r = {center_pos[pg*3], center_pos[pg*3+1], center_pos[pg*3+2], 0.f};
      ((f32x4*)cp4)[pg] = r;
    }
    __syncthreads();
    {
      int k = tid >> 1, g0 = (tid & 1)*4;
      const float* brow = (k < 64) ? (cpe_w2 + k*64) : (Wq + (k-64)*64);
      float sgn = (k < 64) ? 1.f : -1.f;
      float aw[4] = {0.f,0.f,0.f,0.f};
      for (int o = 0; o < 64; o++){
        float bo = brow[o]*sgn;
        #pragma unroll
        for (int gg=0; gg<4; gg++) aw[gg] += bo * sWe[o*8 + g0+gg];
      }
      #pragma unroll
      for (int gg=0; gg<4; gg++) sWT[(g0+gg)*136 + k] = f2bf(aw[gg]);
    }
    for (int e = tid; e < 2176; e += 256){
      int r = e / 136, cc = e % 136;
      if (r >= 8 || cc >= 128) sWT[e] = 0;
    }
    if (tid < 8){
      float s = 0.f;
      for (int o = 0; o < 64; o++) s += (cpe_b2[o] - bq[o]) * sWe[o*8 + tid];
      sCi[tid] = s;
    }
    __syncthreads();

    #pragma unroll 1
    for (int s = 0; s < 4; s++){
      int m0 = m00 + s*64;
      #pragma unroll
      for (int pp = 0; pp < 4; pp++){
        int k = pp*16 + (tid >> 4);
        int nf = (tid & 15)*4;
        f32x4 v = *(const f32x4*)&cfb[(long)k*M_ + m0 + nf];
        sA[(nf+0)*72+k] = f2bf(v[0]); sA[(nf+1)*72+k] = f2bf(v[1]);
        sA[(nf+2)*72+k] = f2bf(v[2]); sA[(nf+3)*72+k] = f2bf(v[3]);
      }
      long c3 = (long)(P0 + s*64 + w*16 + c)*3;
      float cp0 = center_pos[c3], cp1 = center_pos[c3+1], cp2 = center_pos[c3+2];
      __syncthreads();

      bf8v ah[2];
      #pragma unroll
      for (int ks = 0; ks < 2; ks++){
        union { bf8v v; u16 sv[8]; } ua;
        #pragma unroll
        for (int j = 0; j < 8; j++){
          int h = ks*32 + q*8 + j;
          float hv = cp0*sMisc[h] + cp1*sMisc[64+h] + cp2*sMisc[128+h] + sMisc[192+h];
          ua.sv[j] = f2bf(fmaxf(hv, 0.f));
        }
        ah[ks] = ua.v;
      }
      bf8v acf0 = *(const bf8v*)&sA[(w*16+c)*72 + q*8];
      bf8v acf1 = *(const bf8v*)&sA[(w*16+c)*72 + 32 + q*8];

      float ci = (c < 8) ? sCi[c] : 0.f;
      f32x4 aq = {ci, ci, ci, ci};
      {
        bf8v b0 = *(const bf8v*)&sWT[c*136 + q*8];
        bf8v b1 = *(const bf8v*)&sWT[c*136 + 32 + q*8];
        bf8v b2 = *(const bf8v*)&sWT[c*136 + 64 + q*8];
        bf8v b3 = *(const bf8v*)&sWT[c*136 + 96 + q*8];
        aq = __builtin_amdgcn_mfma_f32_16x16x32_bf16(ah[0], b0, aq, 0,0,0);
        aq = __builtin_amdgcn_mfma_f32_16x16x32_bf16(ah[1], b1, aq, 0,0,0);
        aq = __builtin_amdgcn_mfma_f32_16x16x32_bf16(acf0,  b2, aq, 0,0,0);
        aq = __builtin_amdgcn_mfma_f32_16x16x32_bf16(acf1,  b3, aq, 0,0,0);
      }
      __syncthreads();
      if (c < 8){
        #pragma unroll
        for (int r = 0; r < 4; r++) sQ[(w*16 + q*4 + r)*8 + c] = aq[r];
      }
      __syncthreads();
      for (int e = tid; e < 512; e += 256)
        qw[(long)(P0 + s*64)*8 + e] = sQ[e];
      __syncthreads();
    }
  }
}

// ---------------------------------------------------------------------------
// attn_kernel v6 (dual-chain ILP): 2 points/wave/iteration, 4 iterations.
// Two fully independent dependency chains (a,b) with disjoint per-wave LDS
// sub-tiles; each chain's LDS round-trips and shfl latencies are covered by
// the twin chain's issue stream.  Prefetch one PAIR ahead (same 2-point
// pipeline depth as v5).  Named-scalar rotation, no arrays-with-runtime-index.
// ---------------------------------------------------------------------------
__global__ __launch_bounds__(256) void attn_kernel(
    const float* __restrict__ cp4, const float* __restrict__ pos4,
    const int* __restrict__ idx,
    const float* __restrict__ pe_w1, const float* __restrict__ pe_s, const float* __restrict__ pe_b,
    const float* __restrict__ pe_w2, const float* __restrict__ pe_b2,
    const float* __restrict__ we_w1, const float* __restrict__ we_s, const float* __restrict__ we_b,
    const float* __restrict__ we_w2, const float* __restrict__ we_b2,
    const u16* __restrict__ xk, const u16* __restrict__ xv, const float* __restrict__ qw,
    float* __restrict__ out)
{
  int tid = threadIdx.x;
  __shared__ float s_w1f[192], s_pb[64], s_pb2[64], s_ww2[64];
  __shared__ float s_ws8[8], s_wb8[8], s_wb28[8];
  __shared__ f32x4 s_dyn4[1536];   // union: stage 11520 B / per-wave 4*6144 B
  __shared__ float s_tile[32*66];

  char* dynb = (char*)s_dyn4;

  if (tid < 64){
    float sc = pe_s[tid];
    s_w1f[tid]     = pe_w1[tid]*sc;
    s_w1f[64+tid]  = pe_w1[64+tid]*sc;
    s_w1f[128+tid] = pe_w1[128+tid]*sc;
    s_pb[tid]  = pe_b[tid];
    s_pb2[tid] = pe_b2[tid];
    s_ww2[tid] = we_w2[tid];
  }
  if (tid >= 64 && tid < 72){
    int g = tid-64;
    s_ws8[g]=we_s[g]; s_wb8[g]=we_b[g]; s_wb28[g]=we_b2[g];
  }
  // stage pe_w2^T [col o][k] stride 72, f16
  u16* stg = (u16*)dynb;
  #pragma unroll
  for (int pp = 0; pp < 4; pp++){
    int row = pp*16 + (tid >> 4);
    int colf = (tid & 15)*4;
    f32x4 v = *(const f32x4*)&pe_w2[row*64 + colf];
    stg[(colf+0)*72+row] = f2h(v[0]); stg[(colf+1)*72+row] = f2h(v[1]);
    stg[(colf+2)*72+row] = f2h(v[2]); stg[(colf+3)*72+row] = f2h(v[3]);
  }
  // stage we_w1^T rows 0..7 (bf16), zero rows 8..15
  u16* stg2 = (u16*)(dynb + 9216);
  for (int e = tid; e < 512; e += 256){
    int k = e >> 3, cc = e & 7;
    stg2[cc*72 + k] = f2bf(we_w1[e]);
  }
  for (int e = tid; e < 576; e += 256) stg2[576 + e] = 0;
  __syncthreads();

  int w = tid >> 6, l = tid & 63, c = l & 15, q = l >> 4, c8 = c & 7;

  f16x8 pw2f[4][2];
  bf8v ww1f[2];
  f16x8 w2B, hz8;
  #pragma unroll
  for (int t = 0; t < 4; t++){
    pw2f[t][0] = *(const f16x8*)&stg[(t*16+c)*72 + q*8];
    pw2f[t][1] = *(const f16x8*)&stg[(t*16+c)*72 + 32 + q*8];
  }
  ww1f[0] = *(const bf8v*)&stg2[c*72 + q*8];
  ww1f[1] = *(const bf8v*)&stg2[c*72 + 32 + q*8];
  {
    union { f16x8 v; u16 s[8]; } uu;
    #pragma unroll
    for (int j = 0; j < 8; j++)
      uu.s[j] = (q == 0 && c < 8) ? f2h(s_ww2[j*8 + c]) : (u16)0;
    w2B = uu.v;
    #pragma unroll
    for (int j = 0; j < 8; j++) uu.s[j] = 0;
    hz8 = uu.v;
  }
  // register-resident packed-f16 H1 coefficients (16 o-values per lane)
  h2v cw0[2][4], cw1[2][4], cw2[2][4], cb[2][4];
  #pragma unroll
  for (int ks = 0; ks < 2; ks++)
    #pragma unroll
    for (int jj = 0; jj < 4; jj++){
      int o = ks*32 + q*8 + jj*2;
      cw0[ks][jj] = mkh2(s_w1f[o],     s_w1f[o+1]);
      cw1[ks][jj] = mkh2(s_w1f[64+o],  s_w1f[65+o]);
      cw2[ks][jj] = mkh2(s_w1f[128+o], s_w1f[129+o]);
      cb [ks][jj] = mkh2(s_pb[o],      s_pb[o+1]);
    }
  float ws_c = s_ws8[c8], wb_c = s_wb8[c8], wb2_c = s_wb28[c8];
  float pb2l = s_pb2[l];
  h2v hz2 = {(_Float16)0.f, (_Float16)0.f};
  __syncthreads();   // stage region -> per-wave tiles

  // per-wave dual tiles: set = { sv16 u16 16x68 (2176B) | swt f32 8x20 (640B) | sh f16 16x8 (256B) } = 3072 B
  u16*  sva  = (u16*) (dynb + w*6144);
  float* swta = (float*)(dynb + w*6144 + 2176);
  u16*  sha  = (u16*) (dynb + w*6144 + 2816);
  u16*  svb  = (u16*) (dynb + w*6144 + 3072);
  float* swtb = (float*)(dynb + w*6144 + 5248);
  u16*  shb  = (u16*) (dynb + w*6144 + 5888);

  // XCD-aware swizzle (2048 blocks % 8 == 0 -> bijective)
  int blk = blockIdx.x;
  int pbase = (((blk & 7) << 8) | (blk >> 3)) * 32;
  int b = pbase >> 14;
  const u16* xkb = xk + (long)b * N_ * 64;
  const u16* xvb = xv + (long)b * N_ * 64;
  const f32x4* pos4b = ((const f32x4*)pos4) + (long)b * N_;
  int ch = c >> 3;
  int gl = l >> 3;

  int pb0 = pbase + w*8;
  const int*   idxl = idx + (long)pb0*16 + c;
  const float* qwl  = qw  + (long)pb0*8 + c8;
  const f32x4* cp4l = ((const f32x4*)cp4) + pb0;

  // ---- prologue: pair 0 (points 0,1) gathered; idx for pair 1 resolved ----
  int iva = idxl[0];
  int ivb = idxl[16];
  int iv2a = idxl[32];
  int iv2b = idxl[48];
  float qa = qwl[0], qb = qwl[8];
  f32x4 cpa = cp4l[0], cpb = cp4l[1];

  f32x4 ppa = pos4b[iva];
  const u16* kra = xkb + (size_t)iva*64;
  bf8v kaa0 = *(const bf8v*)(kra + q*8);
  bf8v kaa1 = *(const bf8v*)(kra + 32 + q*8);
  const u16* vra = xvb + (size_t)iva*64;
  uint4v vaa0 = *(const uint4v*)(vra + q*8);
  uint4v vaa1 = *(const uint4v*)(vra + 32 + q*8);

  f32x4 ppb = pos4b[ivb];
  const u16* krb = xkb + (size_t)ivb*64;
  bf8v kab0 = *(const bf8v*)(krb + q*8);
  bf8v kab1 = *(const bf8v*)(krb + 32 + q*8);
  const u16* vrb = xvb + (size_t)ivb*64;
  uint4v vab0 = *(const uint4v*)(vrb + q*8);
  uint4v vab1 = *(const uint4v*)(vrb + 32 + q*8);

  #pragma unroll 1
  for (int ii = 0; ii < 4; ii++){
    int i0 = 2*ii, i1 = 2*ii+1;
    // ---- prefetch next pair (addresses iv2a/iv2b resolved last iter) ----
    f32x4 ppna = pos4b[iv2a];
    const u16* krna = xkb + (size_t)iv2a*64;
    bf8v kana0 = *(const bf8v*)(krna + q*8);
    bf8v kana1 = *(const bf8v*)(krna + 32 + q*8);
    const u16* vrna = xvb + (size_t)iv2a*64;
    uint4v vana0 = *(const uint4v*)(vrna + q*8);
    uint4v vana1 = *(const uint4v*)(vrna + 32 + q*8);
    f32x4 ppnb = pos4b[iv2b];
    const u16* krnb = xkb + (size_t)iv2b*64;
    bf8v kanb0 = *(const bf8v*)(krnb + q*8);
    bf8v kanb1 = *(const bf8v*)(krnb + 32 + q*8);
    const u16* vrnb = xvb + (size_t)iv2b*64;
    uint4v vanb0 = *(const uint4v*)(vrnb + q*8);
    uint4v vanb1 = *(const uint4v*)(vrnb + 32 + q*8);
    int na = (ii < 3) ? i0+2 : 7, nb = (ii < 3) ? i1+2 : 7;
    f32x4 cpna = cp4l[na], cpnb = cp4l[nb];
    float qna = qwl[na*8], qnb = qwl[nb*8];
    int n4 = (ii < 2) ? i0+4 : 7, n5 = (ii < 2) ? i1+4 : 7;
    int iv4a = idxl[n4*16], iv4b = idxl[n5*16];

    // ---- V raw bf16 tiles (both chains) ----
    *(uint4v*)&sva[c*68 + q*8]      = vaa0;
    *(uint4v*)&sva[c*68 + 32 + q*8] = vaa1;
    *(uint4v*)&svb[c*68 + q*8]      = vab0;
    *(uint4v*)&svb[c*68 + 32 + q*8] = vab1;

    // ---- H1 (both) ----
    float na0 = ppa[0]-cpa[0], na1 = ppa[1]-cpa[1], na2 = ppa[2]-cpa[2];
    float nb0 = ppb[0]-cpb[0], nb1 = ppb[1]-cpb[1], nb2 = ppb[2]-cpb[2];
    h2v na0h = {(_Float16)na0,(_Float16)na0}, na1h = {(_Float16)na1,(_Float16)na1}, na2h = {(_Float16)na2,(_Float16)na2};
    h2v nb0h = {(_Float16)nb0,(_Float16)nb0}, nb1h = {(_Float16)nb1,(_Float16)nb1}, nb2h = {(_Float16)nb2,(_Float16)nb2};
    f16x8 h1fa[2], h1fb[2];
    #pragma unroll
    for (int ks = 0; ks < 2; ks++){
      union { f16x8 v; h2v p[4]; } hua, hub;
      #pragma unroll
      for (int jj = 0; jj < 4; jj++){
        h2v aa = cb[ks][jj];
        aa = na0h*cw0[ks][jj] + aa;
        aa = na1h*cw1[ks][jj] + aa;
        aa = na2h*cw2[ks][jj] + aa;
        hua.p[jj] = __builtin_elementwise_max(aa, hz2);
        h2v ab = cb[ks][jj];
        ab = nb0h*cw0[ks][jj] + ab;
        ab = nb1h*cw1[ks][jj] + ab;
        ab = nb2h*cw2[ks][jj] + ab;
        hub.p[jj] = __builtin_elementwise_max(ab, hz2);
      }
      h1fa[ks] = hua.v;
      h1fb[ks] = hub.v;
    }

    // ---- weight-MLP hidden (both) ----
    f32x4 h2aa = {qa, qa, qa, qa};
    h2aa = __builtin_amdgcn_mfma_f32_16x16x32_bf16(kaa0, ww1f[0], h2aa, 0,0,0);
    h2aa = __builtin_amdgcn_mfma_f32_16x16x32_bf16(kaa1, ww1f[1], h2aa, 0,0,0);
    f32x4 h2ab = {qb, qb, qb, qb};
    h2ab = __builtin_amdgcn_mfma_f32_16x16x32_bf16(kab0, ww1f[0], h2ab, 0,0,0);
    h2ab = __builtin_amdgcn_mfma_f32_16x16x32_bf16(kab1, ww1f[1], h2ab, 0,0,0);

    // hidden relu -> sh (both)
    if (c < 8){
      #pragma unroll
      for (int r = 0; r < 4; r++){
        sha[(q*4+r)*8 + c] = f2h(fmaxf(h2aa[r]*ws_c + wb_c, 0.f));
        shb[(q*4+r)*8 + c] = f2h(fmaxf(h2ab[r]*ws_c + wb_c, 0.f));
      }
    }
    f16x8 hrowa = *(const f16x8*)&sha[c*8];
    f16x8 hrowb = *(const f16x8*)&shb[c*8];
    f16x8 ahfa = (q == 0) ? hrowa : hz8;
    f16x8 ahfb = (q == 0) ? hrowb : hz8;

    // logits (both)
    f32x4 wlva = {wb2_c, wb2_c, wb2_c, wb2_c};
    wlva = __builtin_amdgcn_mfma_f32_16x16x32_f16(ahfa, w2B, wlva, 0,0,0);
    f32x4 wlvb = {wb2_c, wb2_c, wb2_c, wb2_c};
    wlvb = __builtin_amdgcn_mfma_f32_16x16x32_f16(ahfb, w2B, wlvb, 0,0,0);

    // softmax (both; shfl latencies overlap across chains)
    float ea0 = exp2f(wlva[0]*1.44269504f);
    float ea1 = exp2f(wlva[1]*1.44269504f);
    float ea2 = exp2f(wlva[2]*1.44269504f);
    float ea3 = exp2f(wlva[3]*1.44269504f);
    float eb0 = exp2f(wlvb[0]*1.44269504f);
    float eb1 = exp2f(wlvb[1]*1.44269504f);
    float eb2 = exp2f(wlvb[2]*1.44269504f);
    float eb3 = exp2f(wlvb[3]*1.44269504f);
    float sma = ea0+ea1+ea2+ea3;
    float smb = eb0+eb1+eb2+eb3;
    sma += __shfl_xor(sma, 16, 64);
    smb += __shfl_xor(smb, 16, 64);
    sma += __shfl_xor(sma, 32, 64);
    smb += __shfl_xor(smb, 32, 64);
    float rna = 1.0f / sma;
    float rnb = 1.0f / smb;
    if (c < 8){
      f32x4 eva = {ea0*rna, ea1*rna, ea2*rna, ea3*rna};
      *(f32x4*)&swta[c*20 + q*4] = eva;
      f32x4 evb = {eb0*rnb, eb1*rnb, eb2*rnb, eb3*rnb};
      *(f32x4*)&swtb[c*20 + q*4] = evb;
    }

    // ---- P parts (both) ----
    float ova[4], ovb[4];
    #pragma unroll
    for (int t = 0; t < 4; t++){
      f32x4 za = {0.f,0.f,0.f,0.f};
      za = __builtin_amdgcn_mfma_f32_16x16x32_f16(h1fa[0], pw2f[t][0], za, 0,0,0);
      za = __builtin_amdgcn_mfma_f32_16x16x32_f16(h1fa[1], pw2f[t][1], za, 0,0,0);
      f32x4 wva = *(const f32x4*)&swta[(t*2+ch)*20 + q*4];
      ova[t] = za[0]*wva[0] + za[1]*wva[1] + za[2]*wva[2] + za[3]*wva[3];
      f32x4 zb = {0.f,0.f,0.f,0.f};
      zb = __builtin_amdgcn_mfma_f32_16x16x32_f16(h1fb[0], pw2f[t][0], zb, 0,0,0);
      zb = __builtin_amdgcn_mfma_f32_16x16x32_f16(h1fb[1], pw2f[t][1], zb, 0,0,0);
      f32x4 wvb = *(const f32x4*)&swtb[(t*2+ch)*20 + q*4];
      ovb[t] = zb[0]*wvb[0] + zb[1]*wvb[1] + zb[2]*wvb[2] + zb[3]*wvb[3];
    }
    #pragma unroll
    for (int t = 0; t < 4; t++){
      ova[t] += __shfl_xor(ova[t], 16, 64);
      ovb[t] += __shfl_xor(ovb[t], 16, 64);
      ova[t] += __shfl_xor(ova[t], 32, 64);
      ovb[t] += __shfl_xor(ovb[t], 32, 64);
    }
    float ovsela = ova[0];
    ovsela = (q==1) ? ova[1] : ovsela;
    ovsela = (q==2) ? ova[2] : ovsela;
    ovsela = (q==3) ? ova[3] : ovsela;
    float ovselb = ovb[0];
    ovselb = (q==1) ? ovb[1] : ovselb;
    ovselb = (q==2) ? ovb[2] : ovselb;
    ovselb = (q==3) ? ovb[3] : ovselb;

    // ---- V parts (both) ----
    float vacca = 0.f, vaccb = 0.f;
    {
      const f32x4* wr4a = (const f32x4*)&swta[gl*20];
      const f32x4* wr4b = (const f32x4*)&swtb[gl*20];
      const u16* svla = &sva[l];
      const u16* svlb = &svb[l];
      #pragma unroll
      for (int k4 = 0; k4 < 4; k4++){
        f32x4 wva = wr4a[k4];
        f32x4 wvb = wr4b[k4];
        vacca += bf2f(svla[(4*k4+0)*68])*wva[0];
        vaccb += bf2f(svlb[(4*k4+0)*68])*wvb[0];
        vacca += bf2f(svla[(4*k4+1)*68])*wva[1];
        vaccb += bf2f(svlb[(4*k4+1)*68])*wvb[1];
        vacca += bf2f(svla[(4*k4+2)*68])*wva[2];
        vaccb += bf2f(svlb[(4*k4+2)*68])*wvb[2];
        vacca += bf2f(svla[(4*k4+3)*68])*wva[3];
        vaccb += bf2f(svlb[(4*k4+3)*68])*wvb[3];
      }
    }

    s_tile[(w*8+i0)*66 + l] = ovsela + vacca + pb2l;
    s_tile[(w*8+i1)*66 + l] = ovselb + vaccb + pb2l;

    // rotate (named, static)
    kaa0 = kana0; kaa1 = kana1; vaa0 = vana0; vaa1 = vana1; ppa = ppna; cpa = cpna; qa = qna;
    kab0 = kanb0; kab1 = kanb1; vab0 = vanb0; vab1 = vanb1; ppb = ppnb; cpb = cpnb; qb = qnb;
    iv2a = iv4a; iv2b = iv4b;
  }
  __syncthreads();

  // coalesced transposed store: out[b][o][m0+pt]
  int o0 = tid >> 5, pt = tid & 31;
  int m0 = pbase & (M_-1);
  long outb = ((long)b*64) * M_ + m0 + pt;
  #pragma unroll
  for (int ii = 0; ii < 8; ii++){
    int o = o0*8 + ii;
    out[outb + (long)o*M_] = s_tile[pt*66 + o];
  }
}

extern "C" void kernel_launch(void* const* d_in, const int* in_sizes, int n_in,
                              void* d_out, int out_size, void* d_ws, size_t ws_size,
                              hipStream_t stream) {
  const float* center_pos = (const float*)d_in[0];
  const float* center_fea = (const float*)d_in[1];
  const float* pos        = (const float*)d_in[2];
  const float* fea        = (const float*)d_in[3];
  const int*   idx        = (const int*)d_in[4];
  const float* Wq = (const float*)d_in[5];   const float* bq = (const float*)d_in[6];
  const float* Wk = (const float*)d_in[7];   const float* bk = (const float*)d_in[8];
  const float* Wv = (const float*)d_in[9];   const float* bv = (const float*)d_in[10];
  const float* cpe_w1 = (const float*)d_in[11]; const float* cpe_s = (const float*)d_in[12];
  const float* cpe_b  = (const float*)d_in[13]; const float* cpe_w2 = (const float*)d_in[14];
  const float* cpe_b2 = (const float*)d_in[15];
  const float* pe_w1 = (const float*)d_in[16]; const float* pe_s = (const float*)d_in[17];
  const float* pe_b  = (const float*)d_in[18]; const float* pe_w2 = (const float*)d_in[19];
  const float* pe_b2 = (const float*)d_in[20];
  const float* we_w1 = (const float*)d_in[21]; const float* we_s = (const float*)d_in[22];
  const float* we_b  = (const float*)d_in[23]; const float* we_w2 = (const float*)d_in[24];
  const float* we_b2 = (const float*)d_in[25];

  // ws: xk u16 | xv u16 | qw f32 | pos4 f32x4 | cp4 f32x4
  const size_t SZ = (size_t)B_*N_*64;
  u16* xk = (u16*)d_ws;
  u16* xv = xk + SZ;
  float* qwp = (float*)(xv + SZ);
  float* pos4p = qwp + (size_t)B_*M_*8;
  float* cp4p  = pos4p + (size_t)B_*N_*4;
  float* outp = (float*)d_out;

  hipLaunchKernelGGL(pre_kernel, dim3(512), dim3(256), 0, stream,
      center_pos, center_fea, pos, fea, Wq, bq, Wk, bk, Wv, bv,
      cpe_w1, cpe_s, cpe_b, cpe_w2, cpe_b2, we_w1,
      xk, xv, qwp, pos4p, cp4p);
  hipLaunchKernelGGL(attn_kernel, dim3(2048), dim3(256), 0, stream,
      cp4p, pos4p, idx, pe_w1, pe_s, pe_b, pe_w2, pe_b2,
      we_w1, we_s, we_b, we_w2, we_b2, xk, xv, qwp, outp);
}

// Round 8
// 203.001 us; speedup vs baseline: 1.0343x; 1.0343x over previous
//
#include <hip/hip_runtime.h>
#include <hip/hip_bf16.h>

typedef unsigned short u16;
typedef __attribute__((ext_vector_type(8))) __bf16 bf8v;
typedef __attribute__((ext_vector_type(8))) _Float16 f16x8;
typedef __attribute__((ext_vector_type(2))) _Float16 h2v;
typedef __attribute__((ext_vector_type(4))) float f32x4;
typedef __attribute__((ext_vector_type(4))) unsigned uint4v;

#define B_ 4
#define N_ 16384
#define M_ 16384
#define K_ 16
#define C_ 64
#define O_ 64
#define G_ 8

__device__ __forceinline__ float bf2f(u16 x){
  union { unsigned u; float f; } v; v.u = ((unsigned)x) << 16; return v.f;
}
__device__ __forceinline__ u16 f2bf(float f){
  union { float f; unsigned u; } v; v.f = f;
  unsigned u = v.u;
  return (u16)((u + 0x7FFFu + ((u >> 16) & 1u)) >> 16);
}
__device__ __forceinline__ u16 f2h(float f){
  union { _Float16 h; u16 u; } v; v.h = (_Float16)f; return v.u;
}
__device__ __forceinline__ h2v mkh2(float a, float b){
  h2v r = {(_Float16)a, (_Float16)b}; return r;
}

// ---------------------------------------------------------------------------
// pre_kernel (round-2/3 version, best measured residue): blocks [0,256) KV
// (+pos4 pack), [256,512) QC (+cp4 pack, inline Bw setup).  256 points/block.
// ---------------------------------------------------------------------------
__global__ __launch_bounds__(256) void pre_kernel(
    const float* __restrict__ center_pos, const float* __restrict__ center_fea,
    const float* __restrict__ pos, const float* __restrict__ fea,
    const float* __restrict__ Wq, const float* __restrict__ bq,
    const float* __restrict__ Wk, const float* __restrict__ bk,
    const float* __restrict__ Wv, const float* __restrict__ bv,
    const float* __restrict__ cpe_w1, const float* __restrict__ cpe_s, const float* __restrict__ cpe_b,
    const float* __restrict__ cpe_w2, const float* __restrict__ cpe_b2,
    const float* __restrict__ we_w1,
    u16* __restrict__ xk, u16* __restrict__ xv, float* __restrict__ qw,
    float* __restrict__ pos4, float* __restrict__ cp4)
{
  __shared__ u16 sWT[128*72];
  __shared__ u16 sA[64*72];
  __shared__ u16 sOut[64*136];
  __shared__ float sMisc[256];
  __shared__ float sCi[8];
  int tid = threadIdx.x;
  int l = tid & 63, w = tid >> 6, c = l & 15, q = l >> 4;
  int blk = blockIdx.x;

  if (blk < 256){
    int P0 = blk * 256; int b = P0 >> 14; int n00 = P0 & (N_-1);
    const float* fb = fea + (long)b*C_*N_;
    for (int e = tid; e < 8192; e += 256){
      int k = e >> 7, col = e & 127;
      float v = (col < 64) ? Wk[k*64 + col] : Wv[k*64 + (col-64)];
      sWT[col*72 + k] = f2bf(v);
    }
    if (tid < 128) sMisc[tid] = (tid < 64) ? bk[tid] : bv[tid-64];
    {
      long pg = (long)P0 + tid;
      f32x4 r = {pos[pg*3], pos[pg*3+1], pos[pg*3+2], 0.f};
      ((f32x4*)pos4)[pg] = r;
    }

    #pragma unroll 1
    for (int s = 0; s < 4; s++){
      int n0 = n00 + s*64;
      #pragma unroll
      for (int pp = 0; pp < 4; pp++){
        int k = pp*16 + (tid >> 4);
        int nf = (tid & 15)*4;
        f32x4 v = *(const f32x4*)&fb[(long)k*N_ + n0 + nf];
        sA[(nf+0)*72+k] = f2bf(v[0]); sA[(nf+1)*72+k] = f2bf(v[1]);
        sA[(nf+2)*72+k] = f2bf(v[2]); sA[(nf+3)*72+k] = f2bf(v[3]);
      }
      __syncthreads();

      bf8v af0 = *(const bf8v*)&sA[(w*16+c)*72 + q*8];
      bf8v af1 = *(const bf8v*)&sA[(w*16+c)*72 + 32 + q*8];
      f32x4 acc[8];
      #pragma unroll
      for (int t = 0; t < 8; t++){
        float bb = sMisc[16*t + c];
        f32x4 a_ = {bb, bb, bb, bb};
        bf8v b0 = *(const bf8v*)&sWT[(16*t + c)*72 + q*8];
        bf8v b1 = *(const bf8v*)&sWT[(16*t + c)*72 + 32 + q*8];
        a_ = __builtin_amdgcn_mfma_f32_16x16x32_bf16(af0, b0, a_, 0,0,0);
        a_ = __builtin_amdgcn_mfma_f32_16x16x32_bf16(af1, b1, a_, 0,0,0);
        acc[t] = a_;
      }
      #pragma unroll
      for (int t = 0; t < 8; t++)
        #pragma unroll
        for (int r = 0; r < 4; r++)
          sOut[(w*16 + q*4 + r)*136 + 16*t + c] = f2bf(acc[t][r]);
      __syncthreads();

      #pragma unroll
      for (int rep = 0; rep < 4; rep++){
        int chunk = rep*256 + tid;
        int pt = chunk >> 4, c8i = chunk & 15;
        uint4v val = *(const uint4v*)&sOut[pt*136 + c8i*8];
        int col8 = c8i*8;
        long row = (long)P0 + s*64 + pt;
        if (col8 < 64) *(uint4v*)(xk + row*64 + col8)      = val;
        else           *(uint4v*)(xv + row*64 + (col8-64)) = val;
      }
      __syncthreads();
    }
  } else {
    int P0 = (blk - 256) * 256; int b = P0 >> 14; int m00 = P0 & (M_-1);
    const float* cfb = center_fea + (long)b*C_*M_;
    float* sWe = (float*)sOut;
    float* sQ  = (float*)sOut;
    for (int e = tid; e < 512; e += 256) sWe[e] = we_w1[e];
    if (tid < 64){
      float sc = cpe_s[tid];
      sMisc[tid]     = cpe_w1[tid]*sc;
      sMisc[64+tid]  = cpe_w1[64+tid]*sc;
      sMisc[128+tid] = cpe_w1[128+tid]*sc;
      sMisc[192+tid] = cpe_b[tid];
    }
    {
      long pg = (long)P0 + tid;
      f32x4 r = {center_pos[pg*3], center_pos[pg*3+1], center_pos[pg*3+2], 0.f};
      ((f32x4*)cp4)[pg] = r;
    }
    __syncthreads();
    {
      int k = tid >> 1, g0 = (tid & 1)*4;
      const float* brow = (k < 64) ? (cpe_w2 + k*64) : (Wq + (k-64)*64);
      float sgn = (k < 64) ? 1.f : -1.f;
      float aw[4] = {0.f,0.f,0.f,0.f};
      for (int o = 0; o < 64; o++){
        float bo = brow[o]*sgn;
        #pragma unroll
        for (int gg=0; gg<4; gg++) aw[gg] += bo * sWe[o*8 + g0+gg];
      }
      #pragma unroll
      for (int gg=0; gg<4; gg++) sWT[(g0+gg)*136 + k] = f2bf(aw[gg]);
    }
    for (int e = tid; e < 2176; e += 256){
      int r = e / 136, cc = e % 136;
      if (r >= 8 || cc >= 128) sWT[e] = 0;
    }
    if (tid < 8){
      float s = 0.f;
      for (int o = 0; o < 64; o++) s += (cpe_b2[o] - bq[o]) * sWe[o*8 + tid];
      sCi[tid] = s;
    }
    __syncthreads();

    #pragma unroll 1
    for (int s = 0; s < 4; s++){
      int m0 = m00 + s*64;
      #pragma unroll
      for (int pp = 0; pp < 4; pp++){
        int k = pp*16 + (tid >> 4);
        int nf = (tid & 15)*4;
        f32x4 v = *(const f32x4*)&cfb[(long)k*M_ + m0 + nf];
        sA[(nf+0)*72+k] = f2bf(v[0]); sA[(nf+1)*72+k] = f2bf(v[1]);
        sA[(nf+2)*72+k] = f2bf(v[2]); sA[(nf+3)*72+k] = f2bf(v[3]);
      }
      long c3 = (long)(P0 + s*64 + w*16 + c)*3;
      float cp0 = center_pos[c3], cp1 = center_pos[c3+1], cp2 = center_pos[c3+2];
      __syncthreads();

      bf8v ah[2];
      #pragma unroll
      for (int ks = 0; ks < 2; ks++){
        union { bf8v v; u16 sv[8]; } ua;
        #pragma unroll
        for (int j = 0; j < 8; j++){
          int h = ks*32 + q*8 + j;
          float hv = cp0*sMisc[h] + cp1*sMisc[64+h] + cp2*sMisc[128+h] + sMisc[192+h];
          ua.sv[j] = f2bf(fmaxf(hv, 0.f));
        }
        ah[ks] = ua.v;
      }
      bf8v acf0 = *(const bf8v*)&sA[(w*16+c)*72 + q*8];
      bf8v acf1 = *(const bf8v*)&sA[(w*16+c)*72 + 32 + q*8];

      float ci = (c < 8) ? sCi[c] : 0.f;
      f32x4 aq = {ci, ci, ci, ci};
      {
        bf8v b0 = *(const bf8v*)&sWT[c*136 + q*8];
        bf8v b1 = *(const bf8v*)&sWT[c*136 + 32 + q*8];
        bf8v b2 = *(const bf8v*)&sWT[c*136 + 64 + q*8];
        bf8v b3 = *(const bf8v*)&sWT[c*136 + 96 + q*8];
        aq = __builtin_amdgcn_mfma_f32_16x16x32_bf16(ah[0], b0, aq, 0,0,0);
        aq = __builtin_amdgcn_mfma_f32_16x16x32_bf16(ah[1], b1, aq, 0,0,0);
        aq = __builtin_amdgcn_mfma_f32_16x16x32_bf16(acf0,  b2, aq, 0,0,0);
        aq = __builtin_amdgcn_mfma_f32_16x16x32_bf16(acf1,  b3, aq, 0,0,0);
      }
      __syncthreads();
      if (c < 8){
        #pragma unroll
        for (int r = 0; r < 4; r++) sQ[(w*16 + q*4 + r)*8 + c] = aq[r];
      }
      __syncthreads();
      for (int e = tid; e < 512; e += 256)
        qw[(long)(P0 + s*64)*8 + e] = sQ[e];
      __syncthreads();
    }
  }
}

// ---------------------------------------------------------------------------
// attn_kernel v8: round-3 structure (best measured: XCD swizzle, depth-2
// gather pipeline, f32 sv tile) + TRANSPOSED hidden MFMA:
//   H^T = mfma(A=we_w1^T (ww1f regs), B=K^T (ka regs as-gathered))
//   -> lane (q,c) holds H[nbr=c][g=q*4+r]; logits A-operand assembled with
//   ONE shfl_xor(16) of packed-f16 pairs instead of the sh LDS round-trip
//   (which also drained the V-tile ds_writes via lgkmcnt).
//   qw bias folds into the accumulator init as f32x4 (rows g=q*4+r).
// ---------------------------------------------------------------------------
__global__ __launch_bounds__(256) void attn_kernel(
    const float* __restrict__ cp4, const float* __restrict__ pos4,
    const int* __restrict__ idx,
    const float* __restrict__ pe_w1, const float* __restrict__ pe_s, const float* __restrict__ pe_b,
    const float* __restrict__ pe_w2, const float* __restrict__ pe_b2,
    const float* __restrict__ we_w1, const float* __restrict__ we_s, const float* __restrict__ we_b,
    const float* __restrict__ we_w2, const float* __restrict__ we_b2,
    const u16* __restrict__ xk, const u16* __restrict__ xv, const float* __restrict__ qw,
    float* __restrict__ out)
{
  int tid = threadIdx.x;
  __shared__ float s_w1f[192], s_pb[64], s_pb2[64], s_ww2[64];
  __shared__ float s_ws8[8], s_wb8[8], s_wb28[8];
  __shared__ f32x4 s_dyn4[1312];   // union: stage 11520 B / per-wave 4*5248 B
  __shared__ float s_tile[32*66];

  char* dynb = (char*)s_dyn4;

  if (tid < 64){
    float sc = pe_s[tid];
    s_w1f[tid]     = pe_w1[tid]*sc;
    s_w1f[64+tid]  = pe_w1[64+tid]*sc;
    s_w1f[128+tid] = pe_w1[128+tid]*sc;
    s_pb[tid]  = pe_b[tid];
    s_pb2[tid] = pe_b2[tid];
    s_ww2[tid] = we_w2[tid];
  }
  if (tid >= 64 && tid < 72){
    int g = tid-64;
    s_ws8[g]=we_s[g]; s_wb8[g]=we_b[g]; s_wb28[g]=we_b2[g];
  }
  // stage pe_w2^T [col o][k] stride 72, f16
  u16* stg = (u16*)dynb;
  #pragma unroll
  for (int pp = 0; pp < 4; pp++){
    int row = pp*16 + (tid >> 4);
    int colf = (tid & 15)*4;
    f32x4 v = *(const f32x4*)&pe_w2[row*64 + colf];
    stg[(colf+0)*72+row] = f2h(v[0]); stg[(colf+1)*72+row] = f2h(v[1]);
    stg[(colf+2)*72+row] = f2h(v[2]); stg[(colf+3)*72+row] = f2h(v[3]);
  }
  // stage we_w1^T rows 0..7 (bf16), zero rows 8..15
  u16* stg2 = (u16*)(dynb + 9216);
  for (int e = tid; e < 512; e += 256){
    int k = e >> 3, cc = e & 7;
    stg2[cc*72 + k] = f2bf(we_w1[e]);
  }
  for (int e = tid; e < 576; e += 256) stg2[576 + e] = 0;
  __syncthreads();

  int w = tid >> 6, l = tid & 63, c = l & 15, q = l >> 4, c8 = c & 7;

  f16x8 pw2f[4][2];
  bf8v ww1f[2];
  f16x8 w2B, hz8;
  #pragma unroll
  for (int t = 0; t < 4; t++){
    pw2f[t][0] = *(const f16x8*)&stg[(t*16+c)*72 + q*8];
    pw2f[t][1] = *(const f16x8*)&stg[(t*16+c)*72 + 32 + q*8];
  }
  ww1f[0] = *(const bf8v*)&stg2[c*72 + q*8];
  ww1f[1] = *(const bf8v*)&stg2[c*72 + 32 + q*8];
  {
    union { f16x8 v; u16 s[8]; } uu;
    #pragma unroll
    for (int j = 0; j < 8; j++)
      uu.s[j] = (q == 0 && c < 8) ? f2h(s_ww2[j*8 + c]) : (u16)0;
    w2B = uu.v;
    #pragma unroll
    for (int j = 0; j < 8; j++) uu.s[j] = 0;
    hz8 = uu.v;
  }
  // register-resident packed-f16 H1 coefficients (16 o-values per lane)
  h2v cw0[2][4], cw1[2][4], cw2[2][4], cb[2][4];
  #pragma unroll
  for (int ks = 0; ks < 2; ks++)
    #pragma unroll
    for (int jj = 0; jj < 4; jj++){
      int o = ks*32 + q*8 + jj*2;
      cw0[ks][jj] = mkh2(s_w1f[o],     s_w1f[o+1]);
      cw1[ks][jj] = mkh2(s_w1f[64+o],  s_w1f[65+o]);
      cw2[ks][jj] = mkh2(s_w1f[128+o], s_w1f[129+o]);
      cb [ks][jj] = mkh2(s_pb[o],      s_pb[o+1]);
    }
  // relu scale/bias for TRANSPOSED hidden rows g=q*4+r (zero for q>=2)
  int qok = (q < 2);
  int gq = (q & 1)*4;
  float wsr0 = qok ? s_ws8[gq+0] : 0.f, wbr0 = qok ? s_wb8[gq+0] : 0.f;
  float wsr1 = qok ? s_ws8[gq+1] : 0.f, wbr1 = qok ? s_wb8[gq+1] : 0.f;
  float wsr2 = qok ? s_ws8[gq+2] : 0.f, wbr2 = qok ? s_wb8[gq+2] : 0.f;
  float wsr3 = qok ? s_ws8[gq+3] : 0.f, wbr3 = qok ? s_wb8[gq+3] : 0.f;
  float wb2_c = s_wb28[c8];
  float pb2l = s_pb2[l];
  h2v hz2 = {(_Float16)0.f, (_Float16)0.f};
  __syncthreads();   // stage region -> per-wave tiles

  // per-wave tile pointers: sv f32 16x68 (4352) | swt f32 8x20 (640)
  float* sv  = (float*)(dynb + w*5248);
  float* swt = (float*)(dynb + w*5248 + 4352);

  // XCD-aware swizzle (2048 blocks % 8 == 0 -> bijective)
  int blk = blockIdx.x;
  int pbase = (((blk & 7) << 8) | (blk >> 3)) * 32;
  int b = pbase >> 14;
  const u16* xkb = xk + (long)b * N_ * 64;
  const u16* xvb = xv + (long)b * N_ * 64;
  const f32x4* pos4b = ((const f32x4*)pos4) + (long)b * N_;
  int ch = c >> 3;
  int gl = l >> 3;

  // scalar streams: base + immediate offsets
  int pb0 = pbase + w*8;
  const int*   idxl = idx + (long)pb0*16 + c;
  const f32x4* qwl4 = ((const f32x4*)(qw + (long)pb0*8)) + (q & 1);
  const f32x4* cp4l = ((const f32x4*)cp4) + pb0;

  // ---- prologue: idx 3 deep, scattered gathers 2 deep ----
  int iv0 = idxl[0];
  int ivt = idxl[16];
  int iv2 = idxl[32];
  f32x4 qvA = qwl4[0];
  f32x4 qvB = qwl4[2];
  f32x4 cpv = cp4l[0];
  // point 0 -> set A
  f32x4 ppA = pos4b[iv0];
  const u16* krA = xkb + (size_t)iv0*64;
  bf8v kaA0 = *(const bf8v*)(krA + q*8);
  bf8v kaA1 = *(const bf8v*)(krA + 32 + q*8);
  const u16* vrA = xvb + (size_t)iv0*64;
  uint4v vaA0 = *(const uint4v*)(vrA + q*8);
  uint4v vaA1 = *(const uint4v*)(vrA + 32 + q*8);
  // point 1 -> set B
  f32x4 ppB = pos4b[ivt];
  const u16* krB = xkb + (size_t)ivt*64;
  bf8v kaB0 = *(const bf8v*)(krB + q*8);
  bf8v kaB1 = *(const bf8v*)(krB + 32 + q*8);
  const u16* vrB = xvb + (size_t)ivt*64;
  uint4v vaB0 = *(const uint4v*)(vrB + q*8);
  uint4v vaB1 = *(const uint4v*)(vrB + 32 + q*8);

  #pragma unroll 1
  for (int i = 0; i < 8; i++){
    // ---- issue gathers for point i+2 (address iv2 resolved 2 iters ago) ----
    f32x4 ppN = pos4b[iv2];
    const u16* krN = xkb + (size_t)iv2*64;
    bf8v kaN0 = *(const bf8v*)(krN + q*8);
    bf8v kaN1 = *(const bf8v*)(krN + 32 + q*8);
    const u16* vrN = xvb + (size_t)iv2*64;
    uint4v vaN0 = *(const uint4v*)(vrN + q*8);
    uint4v vaN1 = *(const uint4v*)(vrN + 32 + q*8);
    // cp/qw depth-1/2 (sequential, cache-friendly)
    int ni = (i < 7) ? i+1 : 7;
    f32x4 cpn = cp4l[ni];
    int n2 = (i < 6) ? i+2 : 7;
    f32x4 qvN = qwl4[n2*2];
    // idx for point i+3
    int n3 = (i < 5) ? i+3 : 7;
    int iv3 = idxl[n3*16];

    // ---- V f32 tile: row k=c, cols q*8.. / 32+q*8.. ----
    {
      unsigned a0 = vaA0[0], a1 = vaA0[1], a2 = vaA0[2], a3 = vaA0[3];
      f32x4 lo0 = {bf2f((u16)a0), bf2f((u16)(a0>>16)), bf2f((u16)a1), bf2f((u16)(a1>>16))};
      f32x4 hi0 = {bf2f((u16)a2), bf2f((u16)(a2>>16)), bf2f((u16)a3), bf2f((u16)(a3>>16))};
      unsigned b0 = vaA1[0], b1 = vaA1[1], b2 = vaA1[2], b3 = vaA1[3];
      f32x4 lo1 = {bf2f((u16)b0), bf2f((u16)(b0>>16)), bf2f((u16)b1), bf2f((u16)(b1>>16))};
      f32x4 hi1 = {bf2f((u16)b2), bf2f((u16)(b2>>16)), bf2f((u16)b3), bf2f((u16)(b3>>16))};
      f32x4* d0 = (f32x4*)&sv[c*68 + q*8];
      d0[0] = lo0; d0[1] = hi0;
      f32x4* d1 = (f32x4*)&sv[c*68 + 32 + q*8];
      d1[0] = lo1; d1[1] = hi1;
    }

    // ---- H1 packed f16 -> f16 A-frags ----
    float np0 = ppA[0] - cpv[0], np1 = ppA[1] - cpv[1], np2 = ppA[2] - cpv[2];
    h2v np0h = {(_Float16)np0, (_Float16)np0};
    h2v np1h = {(_Float16)np1, (_Float16)np1};
    h2v np2h = {(_Float16)np2, (_Float16)np2};
    f16x8 h1f[2];
    #pragma unroll
    for (int ks = 0; ks < 2; ks++){
      union { f16x8 v; h2v p[4]; } hu;
      #pragma unroll
      for (int jj = 0; jj < 4; jj++){
        h2v a = cb[ks][jj];
        a = np0h*cw0[ks][jj] + a;
        a = np1h*cw1[ks][jj] + a;
        a = np2h*cw2[ks][jj] + a;
        hu.p[jj] = __builtin_elementwise_max(a, hz2);
      }
      h1f[ks] = hu.v;
    }

    // ---- weight-MLP hidden, TRANSPOSED (no LDS round-trip) ----
    // H^T[g=q*4+r][nbr=c]; qw bias folded into acc rows (q<2; rows>=8 inert)
    f32x4 h2t = {qvA[0], qvA[1], qvA[2], qvA[3]};
    h2t = __builtin_amdgcn_mfma_f32_16x16x32_bf16(ww1f[0], kaA0, h2t, 0,0,0);
    h2t = __builtin_amdgcn_mfma_f32_16x16x32_bf16(ww1f[1], kaA1, h2t, 0,0,0);
    // relu+scale (per-row g), pack to f16 pairs, swap q0<->q1 via shfl
    h2v hp01 = mkh2(fmaxf(h2t[0]*wsr0 + wbr0, 0.f), fmaxf(h2t[1]*wsr1 + wbr1, 0.f));
    h2v hp23 = mkh2(fmaxf(h2t[2]*wsr2 + wbr2, 0.f), fmaxf(h2t[3]*wsr3 + wbr3, 0.f));
    union { h2v h; int i; } u01, u23, x01, x23;
    u01.h = hp01; u23.h = hp23;
    x01.i = __shfl_xor(u01.i, 16, 64);
    x23.i = __shfl_xor(u23.i, 16, 64);
    f16x8 ahf;
    {
      union { f16x8 v; h2v p[4]; } au;
      au.p[0] = u01.h; au.p[1] = u23.h; au.p[2] = x01.h; au.p[3] = x23.h;
      ahf = (q == 0) ? au.v : hz8;
    }

    // logits via f16 MFMA: wl[r] = logit[k=q*4+r][g=c]
    f32x4 wlv = {wb2_c, wb2_c, wb2_c, wb2_c};
    wlv = __builtin_amdgcn_mfma_f32_16x16x32_f16(ahf, w2B, wlv, 0,0,0);

    // softmax over 16 neighbors (logits O(1), no max-sub)
    float e0 = exp2f(wlv[0]*1.44269504f);
    float e1 = exp2f(wlv[1]*1.44269504f);
    float e2 = exp2f(wlv[2]*1.44269504f);
    float e3 = exp2f(wlv[3]*1.44269504f);
    float sm = e0+e1+e2+e3;
    sm += __shfl_xor(sm, 16, 64);
    sm += __shfl_xor(sm, 32, 64);
    float rn = 1.0f / sm;
    // weights to LDS f32: swt[g=c][k=q*4..q*4+3]
    if (c < 8){
      f32x4 ev = {e0*rn, e1*rn, e2*rn, e3*rn};
      *(f32x4*)&swt[c*20 + q*4] = ev;
    }

    // ---- P part: f16 MFMA, weights from swt, cross-quad reduce ----
    float ov[4];
    #pragma unroll
    for (int t = 0; t < 4; t++){
      f32x4 z = {0.f,0.f,0.f,0.f};
      z = __builtin_amdgcn_mfma_f32_16x16x32_f16(h1f[0], pw2f[t][0], z, 0,0,0);
      z = __builtin_amdgcn_mfma_f32_16x16x32_f16(h1f[1], pw2f[t][1], z, 0,0,0);
      f32x4 wv = *(const f32x4*)&swt[(t*2+ch)*20 + q*4];
      ov[t] = z[0]*wv[0] + z[1]*wv[1] + z[2]*wv[2] + z[3]*wv[3];
    }
    #pragma unroll
    for (int t = 0; t < 4; t++){
      ov[t] += __shfl_xor(ov[t], 16, 64);
      ov[t] += __shfl_xor(ov[t], 32, 64);
    }
    float ovsel = ov[0];
    ovsel = (q==1) ? ov[1] : ovsel;
    ovsel = (q==2) ? ov[2] : ovsel;
    ovsel = (q==3) ? ov[3] : ovsel;

    // ---- V part: per-lane output o=l, 16-tap dot ----
    float vacc = 0.f;
    {
      const f32x4* wr4 = (const f32x4*)&swt[gl*20];
      const float* svl = &sv[l];
      #pragma unroll
      for (int k4 = 0; k4 < 4; k4++){
        f32x4 wv = wr4[k4];
        vacc += svl[(4*k4+0)*68]*wv[0];
        vacc += svl[(4*k4+1)*68]*wv[1];
        vacc += svl[(4*k4+2)*68]*wv[2];
        vacc += svl[(4*k4+3)*68]*wv[3];
      }
    }

    s_tile[(w*8+i)*66 + l] = ovsel + vacc + pb2l;

    // rotate (named, static)
    kaA0 = kaB0; kaA1 = kaB1; vaA0 = vaB0; vaA1 = vaB1; ppA = ppB; qvA = qvB;
    kaB0 = kaN0; kaB1 = kaN1; vaB0 = vaN0; vaB1 = vaN1; ppB = ppN; qvB = qvN;
    cpv = cpn;
    iv2 = iv3;
  }
  __syncthreads();

  // coalesced transposed store: out[b][o][m0+pt]
  int o0 = tid >> 5, pt = tid & 31;
  int m0 = pbase & (M_-1);
  long outb = ((long)b*64) * M_ + m0 + pt;
  #pragma unroll
  for (int ii = 0; ii < 8; ii++){
    int o = o0*8 + ii;
    out[outb + (long)o*M_] = s_tile[pt*66 + o];
  }
}

extern "C" void kernel_launch(void* const* d_in, const int* in_sizes, int n_in,
                              void* d_out, int out_size, void* d_ws, size_t ws_size,
                              hipStream_t stream) {
  const float* center_pos = (const float*)d_in[0];
  const float* center_fea = (const float*)d_in[1];
  const float* pos        = (const float*)d_in[2];
  const float* fea        = (const float*)d_in[3];
  const int*   idx        = (const int*)d_in[4];
  const float* Wq = (const float*)d_in[5];   const float* bq = (const float*)d_in[6];
  const float* Wk = (const float*)d_in[7];   const float* bk = (const float*)d_in[8];
  const float* Wv = (const float*)d_in[9];   const float* bv = (const float*)d_in[10];
  const float* cpe_w1 = (const float*)d_in[11]; const float* cpe_s = (const float*)d_in[12];
  const float* cpe_b  = (const float*)d_in[13]; const float* cpe_w2 = (const float*)d_in[14];
  const float* cpe_b2 = (const float*)d_in[15];
  const float* pe_w1 = (const float*)d_in[16]; const float* pe_s = (const float*)d_in[17];
  const float* pe_b  = (const float*)d_in[18]; const float* pe_w2 = (const float*)d_in[19];
  const float* pe_b2 = (const float*)d_in[20];
  const float* we_w1 = (const float*)d_in[21]; const float* we_s = (const float*)d_in[22];
  const float* we_b  = (const float*)d_in[23]; const float* we_w2 = (const float*)d_in[24];
  const float* we_b2 = (const float*)d_in[25];

  // ws: xk u16 | xv u16 | qw f32 | pos4 f32x4 | cp4 f32x4
  const size_t SZ = (size_t)B_*N_*64;
  u16* xk = (u16*)d_ws;
  u16* xv = xk + SZ;
  float* qwp = (float*)(xv + SZ);
  float* pos4p = qwp + (size_t)B_*M_*8;
  float* cp4p  = pos4p + (size_t)B_*N_*4;
  float* outp = (float*)d_out;

  hipLaunchKernelGGL(pre_kernel, dim3(512), dim3(256), 0, stream,
      center_pos, center_fea, pos, fea, Wq, bq, Wk, bk, Wv, bv,
      cpe_w1, cpe_s, cpe_b, cpe_w2, cpe_b2, we_w1,
      xk, xv, qwp, pos4p, cp4p);
  hipLaunchKernelGGL(attn_kernel, dim3(2048), dim3(256), 0, stream,
      cp4p, pos4p, idx, pe_w1, pe_s, pe_b, pe_w2, pe_b2,
      we_w1, we_s, we_b, we_w2, we_b2, xk, xv, qwp, outp);
}

// Round 9
// 202.873 us; speedup vs baseline: 1.0350x; 1.0006x over previous
//
#include <hip/hip_runtime.h>
#include <hip/hip_bf16.h>

typedef unsigned short u16;
typedef __attribute__((ext_vector_type(8))) __bf16 bf8v;
typedef __attribute__((ext_vector_type(8))) _Float16 f16x8;
typedef __attribute__((ext_vector_type(2))) _Float16 h2v;
typedef __attribute__((ext_vector_type(4))) float f32x4;
typedef __attribute__((ext_vector_type(4))) unsigned uint4v;
typedef __attribute__((ext_vector_type(4))) int int4v;

#define B_ 4
#define N_ 16384
#define M_ 16384
#define K_ 16
#define C_ 64
#define O_ 64
#define G_ 8

__device__ __forceinline__ float bf2f(u16 x){
  union { unsigned u; float f; } v; v.u = ((unsigned)x) << 16; return v.f;
}
__device__ __forceinline__ u16 f2bf(float f){
  union { float f; unsigned u; } v; v.f = f;
  unsigned u = v.u;
  return (u16)((u + 0x7FFFu + ((u >> 16) & 1u)) >> 16);
}
__device__ __forceinline__ u16 f2h(float f){
  union { _Float16 h; u16 u; } v; v.h = (_Float16)f; return v.u;
}
__device__ __forceinline__ h2v mkh2(float a, float b){
  h2v r = {(_Float16)a, (_Float16)b}; return r;
}

// ---------------------------------------------------------------------------
// pre_kernel (round-2/3 version, best measured residue): blocks [0,256) KV
// (+pos4 pack), [256,512) QC (+cp4 pack, inline Bw setup).  256 points/block.
// ---------------------------------------------------------------------------
__global__ __launch_bounds__(256) void pre_kernel(
    const float* __restrict__ center_pos, const float* __restrict__ center_fea,
    const float* __restrict__ pos, const float* __restrict__ fea,
    const float* __restrict__ Wq, const float* __restrict__ bq,
    const float* __restrict__ Wk, const float* __restrict__ bk,
    const float* __restrict__ Wv, const float* __restrict__ bv,
    const float* __restrict__ cpe_w1, const float* __restrict__ cpe_s, const float* __restrict__ cpe_b,
    const float* __restrict__ cpe_w2, const float* __restrict__ cpe_b2,
    const float* __restrict__ we_w1,
    u16* __restrict__ xk, u16* __restrict__ xv, float* __restrict__ qw,
    float* __restrict__ pos4, float* __restrict__ cp4)
{
  __shared__ u16 sWT[128*72];
  __shared__ u16 sA[64*72];
  __shared__ u16 sOut[64*136];
  __shared__ float sMisc[256];
  __shared__ float sCi[8];
  int tid = threadIdx.x;
  int l = tid & 63, w = tid >> 6, c = l & 15, q = l >> 4;
  int blk = blockIdx.x;

  if (blk < 256){
    int P0 = blk * 256; int b = P0 >> 14; int n00 = P0 & (N_-1);
    const float* fb = fea + (long)b*C_*N_;
    for (int e = tid; e < 8192; e += 256){
      int k = e >> 7, col = e & 127;
      float v = (col < 64) ? Wk[k*64 + col] : Wv[k*64 + (col-64)];
      sWT[col*72 + k] = f2bf(v);
    }
    if (tid < 128) sMisc[tid] = (tid < 64) ? bk[tid] : bv[tid-64];
    {
      long pg = (long)P0 + tid;
      f32x4 r = {pos[pg*3], pos[pg*3+1], pos[pg*3+2], 0.f};
      ((f32x4*)pos4)[pg] = r;
    }

    #pragma unroll 1
    for (int s = 0; s < 4; s++){
      int n0 = n00 + s*64;
      #pragma unroll
      for (int pp = 0; pp < 4; pp++){
        int k = pp*16 + (tid >> 4);
        int nf = (tid & 15)*4;
        f32x4 v = *(const f32x4*)&fb[(long)k*N_ + n0 + nf];
        sA[(nf+0)*72+k] = f2bf(v[0]); sA[(nf+1)*72+k] = f2bf(v[1]);
        sA[(nf+2)*72+k] = f2bf(v[2]); sA[(nf+3)*72+k] = f2bf(v[3]);
      }
      __syncthreads();

      bf8v af0 = *(const bf8v*)&sA[(w*16+c)*72 + q*8];
      bf8v af1 = *(const bf8v*)&sA[(w*16+c)*72 + 32 + q*8];
      f32x4 acc[8];
      #pragma unroll
      for (int t = 0; t < 8; t++){
        float bb = sMisc[16*t + c];
        f32x4 a_ = {bb, bb, bb, bb};
        bf8v b0 = *(const bf8v*)&sWT[(16*t + c)*72 + q*8];
        bf8v b1 = *(const bf8v*)&sWT[(16*t + c)*72 + 32 + q*8];
        a_ = __builtin_amdgcn_mfma_f32_16x16x32_bf16(af0, b0, a_, 0,0,0);
        a_ = __builtin_amdgcn_mfma_f32_16x16x32_bf16(af1, b1, a_, 0,0,0);
        acc[t] = a_;
      }
      #pragma unroll
      for (int t = 0; t < 8; t++)
        #pragma unroll
        for (int r = 0; r < 4; r++)
          sOut[(w*16 + q*4 + r)*136 + 16*t + c] = f2bf(acc[t][r]);
      __syncthreads();

      #pragma unroll
      for (int rep = 0; rep < 4; rep++){
        int chunk = rep*256 + tid;
        int pt = chunk >> 4, c8i = chunk & 15;
        uint4v val = *(const uint4v*)&sOut[pt*136 + c8i*8];
        int col8 = c8i*8;
        long row = (long)P0 + s*64 + pt;
        if (col8 < 64) *(uint4v*)(xk + row*64 + col8)      = val;
        else           *(uint4v*)(xv + row*64 + (col8-64)) = val;
      }
      __syncthreads();
    }
  } else {
    int P0 = (blk - 256) * 256; int b = P0 >> 14; int m00 = P0 & (M_-1);
    const float* cfb = center_fea + (long)b*C_*M_;
    float* sWe = (float*)sOut;
    float* sQ  = (float*)sOut;
    for (int e = tid; e < 512; e += 256) sWe[e] = we_w1[e];
    if (tid < 64){
      float sc = cpe_s[tid];
      sMisc[tid]     = cpe_w1[tid]*sc;
      sMisc[64+tid]  = cpe_w1[64+tid]*sc;
      sMisc[128+tid] = cpe_w1[128+tid]*sc;
      sMisc[192+tid] = cpe_b[tid];
    }
    {
      long pg = (long)P0 + tid;
      f32x4 r = {center_pos[pg*3], center_pos[pg*3+1], center_pos[pg*3+2], 0.f};
      ((f32x4*)cp4)[pg] = r;
    }
    __syncthreads();
    {
      int k = tid >> 1, g0 = (tid & 1)*4;
      const float* brow = (k < 64) ? (cpe_w2 + k*64) : (Wq + (k-64)*64);
      float sgn = (k < 64) ? 1.f : -1.f;
      float aw[4] = {0.f,0.f,0.f,0.f};
      for (int o = 0; o < 64; o++){
        float bo = brow[o]*sgn;
        #pragma unroll
        for (int gg=0; gg<4; gg++) aw[gg] += bo * sWe[o*8 + g0+gg];
      }
      #pragma unroll
      for (int gg=0; gg<4; gg++) sWT[(g0+gg)*136 + k] = f2bf(aw[gg]);
    }
    for (int e = tid; e < 2176; e += 256){
      int r = e / 136, cc = e % 136;
      if (r >= 8 || cc >= 128) sWT[e] = 0;
    }
    if (tid < 8){
      float s = 0.f;
      for (int o = 0; o < 64; o++) s += (cpe_b2[o] - bq[o]) * sWe[o*8 + tid];
      sCi[tid] = s;
    }
    __syncthreads();

    #pragma unroll 1
    for (int s = 0; s < 4; s++){
      int m0 = m00 + s*64;
      #pragma unroll
      for (int pp = 0; pp < 4; pp++){
        int k = pp*16 + (tid >> 4);
        int nf = (tid & 15)*4;
        f32x4 v = *(const f32x4*)&cfb[(long)k*M_ + m0 + nf];
        sA[(nf+0)*72+k] = f2bf(v[0]); sA[(nf+1)*72+k] = f2bf(v[1]);
        sA[(nf+2)*72+k] = f2bf(v[2]); sA[(nf+3)*72+k] = f2bf(v[3]);
      }
      long c3 = (long)(P0 + s*64 + w*16 + c)*3;
      float cp0 = center_pos[c3], cp1 = center_pos[c3+1], cp2 = center_pos[c3+2];
      __syncthreads();

      bf8v ah[2];
      #pragma unroll
      for (int ks = 0; ks < 2; ks++){
        union { bf8v v; u16 sv[8]; } ua;
        #pragma unroll
        for (int j = 0; j < 8; j++){
          int h = ks*32 + q*8 + j;
          float hv = cp0*sMisc[h] + cp1*sMisc[64+h] + cp2*sMisc[128+h] + sMisc[192+h];
          ua.sv[j] = f2bf(fmaxf(hv, 0.f));
        }
        ah[ks] = ua.v;
      }
      bf8v acf0 = *(const bf8v*)&sA[(w*16+c)*72 + q*8];
      bf8v acf1 = *(const bf8v*)&sA[(w*16+c)*72 + 32 + q*8];

      float ci = (c < 8) ? sCi[c] : 0.f;
      f32x4 aq = {ci, ci, ci, ci};
      {
        bf8v b0 = *(const bf8v*)&sWT[c*136 + q*8];
        bf8v b1 = *(const bf8v*)&sWT[c*136 + 32 + q*8];
        bf8v b2 = *(const bf8v*)&sWT[c*136 + 64 + q*8];
        bf8v b3 = *(const bf8v*)&sWT[c*136 + 96 + q*8];
        aq = __builtin_amdgcn_mfma_f32_16x16x32_bf16(ah[0], b0, aq, 0,0,0);
        aq = __builtin_amdgcn_mfma_f32_16x16x32_bf16(ah[1], b1, aq, 0,0,0);
        aq = __builtin_amdgcn_mfma_f32_16x16x32_bf16(acf0,  b2, aq, 0,0,0);
        aq = __builtin_amdgcn_mfma_f32_16x16x32_bf16(acf1,  b3, aq, 0,0,0);
      }
      __syncthreads();
      if (c < 8){
        #pragma unroll
        for (int r = 0; r < 4; r++) sQ[(w*16 + q*4 + r)*8 + c] = aq[r];
      }
      __syncthreads();
      for (int e = tid; e < 512; e += 256)
        qw[(long)(P0 + s*64)*8 + e] = sQ[e];
      __syncthreads();
    }
  }
}

// ---------------------------------------------------------------------------
// attn_kernel v9: v8 (transposed hidden MFMA, XCD swizzle, depth-2 K pipeline)
// + V FOLDED INTO THE P MFMA ACCUMULATOR:
//   out = sum_k (pr+nv)*w, and the P MFMA's C/D layout (lane (q,c) holds
//   Z[nbr=q*4+r][o=t*16+c]) lets V enter as the accumulator init.  V is
//   gathered DIRECTLY in that layout from global (16 scalar u16 loads/lane,
//   prefetched 1 iter ahead; neighbor idx quad via one dwordx4, 2 ahead).
//   Deletes the entire sv LDS tile: 2 ds_write_b128 + 16 ds_read taps +
//   4 swt b128 reads + 16 merge FMAs per iteration.  DS ops/iter ~40 -> ~17.
// ---------------------------------------------------------------------------
__global__ __launch_bounds__(256) void attn_kernel(
    const float* __restrict__ cp4, const float* __restrict__ pos4,
    const int* __restrict__ idx,
    const float* __restrict__ pe_w1, const float* __restrict__ pe_s, const float* __restrict__ pe_b,
    const float* __restrict__ pe_w2, const float* __restrict__ pe_b2,
    const float* __restrict__ we_w1, const float* __restrict__ we_s, const float* __restrict__ we_b,
    const float* __restrict__ we_w2, const float* __restrict__ we_b2,
    const u16* __restrict__ xk, const u16* __restrict__ xv, const float* __restrict__ qw,
    float* __restrict__ out)
{
  int tid = threadIdx.x;
  __shared__ float s_w1f[192], s_pb[64], s_pb2[64], s_ww2[64];
  __shared__ float s_ws8[8], s_wb8[8], s_wb28[8];
  __shared__ f32x4 s_dyn4[720];    // union: stage 11520 B / per-wave 4*768 B (swt)
  __shared__ float s_tile[32*66];

  char* dynb = (char*)s_dyn4;

  if (tid < 64){
    float sc = pe_s[tid];
    s_w1f[tid]     = pe_w1[tid]*sc;
    s_w1f[64+tid]  = pe_w1[64+tid]*sc;
    s_w1f[128+tid] = pe_w1[128+tid]*sc;
    s_pb[tid]  = pe_b[tid];
    s_pb2[tid] = pe_b2[tid];
    s_ww2[tid] = we_w2[tid];
  }
  if (tid >= 64 && tid < 72){
    int g = tid-64;
    s_ws8[g]=we_s[g]; s_wb8[g]=we_b[g]; s_wb28[g]=we_b2[g];
  }
  // stage pe_w2^T [col o][k] stride 72, f16
  u16* stg = (u16*)dynb;
  #pragma unroll
  for (int pp = 0; pp < 4; pp++){
    int row = pp*16 + (tid >> 4);
    int colf = (tid & 15)*4;
    f32x4 v = *(const f32x4*)&pe_w2[row*64 + colf];
    stg[(colf+0)*72+row] = f2h(v[0]); stg[(colf+1)*72+row] = f2h(v[1]);
    stg[(colf+2)*72+row] = f2h(v[2]); stg[(colf+3)*72+row] = f2h(v[3]);
  }
  // stage we_w1^T rows 0..7 (bf16), zero rows 8..15
  u16* stg2 = (u16*)(dynb + 9216);
  for (int e = tid; e < 512; e += 256){
    int k = e >> 3, cc = e & 7;
    stg2[cc*72 + k] = f2bf(we_w1[e]);
  }
  for (int e = tid; e < 576; e += 256) stg2[576 + e] = 0;
  __syncthreads();

  int w = tid >> 6, l = tid & 63, c = l & 15, q = l >> 4, c8 = c & 7;

  f16x8 pw2f[4][2];
  bf8v ww1f[2];
  f16x8 w2B, hz8;
  #pragma unroll
  for (int t = 0; t < 4; t++){
    pw2f[t][0] = *(const f16x8*)&stg[(t*16+c)*72 + q*8];
    pw2f[t][1] = *(const f16x8*)&stg[(t*16+c)*72 + 32 + q*8];
  }
  ww1f[0] = *(const bf8v*)&stg2[c*72 + q*8];
  ww1f[1] = *(const bf8v*)&stg2[c*72 + 32 + q*8];
  {
    union { f16x8 v; u16 s[8]; } uu;
    #pragma unroll
    for (int j = 0; j < 8; j++)
      uu.s[j] = (q == 0 && c < 8) ? f2h(s_ww2[j*8 + c]) : (u16)0;
    w2B = uu.v;
    #pragma unroll
    for (int j = 0; j < 8; j++) uu.s[j] = 0;
    hz8 = uu.v;
  }
  // register-resident packed-f16 H1 coefficients (16 o-values per lane)
  h2v cw0[2][4], cw1[2][4], cw2[2][4], cb[2][4];
  #pragma unroll
  for (int ks = 0; ks < 2; ks++)
    #pragma unroll
    for (int jj = 0; jj < 4; jj++){
      int o = ks*32 + q*8 + jj*2;
      cw0[ks][jj] = mkh2(s_w1f[o],     s_w1f[o+1]);
      cw1[ks][jj] = mkh2(s_w1f[64+o],  s_w1f[65+o]);
      cw2[ks][jj] = mkh2(s_w1f[128+o], s_w1f[129+o]);
      cb [ks][jj] = mkh2(s_pb[o],      s_pb[o+1]);
    }
  // relu scale/bias for TRANSPOSED hidden rows g=q*4+r (zero for q>=2)
  int qok = (q < 2);
  int gq = (q & 1)*4;
  float wsr0 = qok ? s_ws8[gq+0] : 0.f, wbr0 = qok ? s_wb8[gq+0] : 0.f;
  float wsr1 = qok ? s_ws8[gq+1] : 0.f, wbr1 = qok ? s_wb8[gq+1] : 0.f;
  float wsr2 = qok ? s_ws8[gq+2] : 0.f, wbr2 = qok ? s_wb8[gq+2] : 0.f;
  float wsr3 = qok ? s_ws8[gq+3] : 0.f, wbr3 = qok ? s_wb8[gq+3] : 0.f;
  float wb2_c = s_wb28[c8];
  float pb2l = s_pb2[l];
  h2v hz2 = {(_Float16)0.f, (_Float16)0.f};
  __syncthreads();   // stage region -> per-wave swt

  // per-wave: swt f32 8x20 (640 B)
  float* swt = (float*)(dynb + w*768);

  // XCD-aware swizzle (2048 blocks % 8 == 0 -> bijective)
  int blk = blockIdx.x;
  int pbase = (((blk & 7) << 8) | (blk >> 3)) * 32;
  int b = pbase >> 14;
  const u16* xkb = xk + (long)b * N_ * 64;
  const u16* xvb = xv + (long)b * N_ * 64;
  const f32x4* pos4b = ((const f32x4*)pos4) + (long)b * N_;
  int ch = c >> 3;

  // scalar streams: base + immediate offsets
  int pb0 = pbase + w*8;
  const int*   idxl = idx + (long)pb0*16 + c;
  const int*   idxq = idx + (long)pb0*16 + q*4;
  const f32x4* qwl4 = ((const f32x4*)(qw + (long)pb0*8)) + (q & 1);
  const f32x4* cp4l = ((const f32x4*)cp4) + pb0;

  // ---- prologue ----
  int iv0 = idxl[0];
  int ivt = idxl[16];
  int iv2 = idxl[32];
  f32x4 qvA = qwl4[0];
  f32x4 qvB = qwl4[2];
  f32x4 cpv = cp4l[0];
  // K/pos point 0 -> set A
  f32x4 ppA = pos4b[iv0];
  const u16* krA = xkb + (size_t)iv0*64;
  bf8v kaA0 = *(const bf8v*)(krA + q*8);
  bf8v kaA1 = *(const bf8v*)(krA + 32 + q*8);
  // K/pos point 1 -> set B
  f32x4 ppB = pos4b[ivt];
  const u16* krB = xkb + (size_t)ivt*64;
  bf8v kaB0 = *(const bf8v*)(krB + q*8);
  bf8v kaB1 = *(const bf8v*)(krB + 32 + q*8);
  // V in acc layout: point 0 now, idx quad for point 1 resolved
  int4v iq0 = *(const int4v*)&idxq[0];
  int4v iqA = *(const int4v*)&idxq[16];
  unsigned vc[4][4];
  #pragma unroll
  for (int r = 0; r < 4; r++){
    const u16* vrow = xvb + (size_t)iq0[r]*64 + c;
    #pragma unroll
    for (int t = 0; t < 4; t++)
      vc[r][t] = vrow[t*16];
  }

  #pragma unroll 1
  for (int i = 0; i < 8; i++){
    // ---- K/pos gathers for point i+2 (address iv2 resolved 2 iters ago) ----
    f32x4 ppN = pos4b[iv2];
    const u16* krN = xkb + (size_t)iv2*64;
    bf8v kaN0 = *(const bf8v*)(krN + q*8);
    bf8v kaN1 = *(const bf8v*)(krN + 32 + q*8);
    // ---- V gathers for point i+1 in acc layout (iqA resolved last iter) ----
    unsigned vn[4][4];
    #pragma unroll
    for (int r = 0; r < 4; r++){
      const u16* vrow = xvb + (size_t)iqA[r]*64 + c;
      #pragma unroll
      for (int t = 0; t < 4; t++)
        vn[r][t] = vrow[t*16];
    }
    int4v iqB = *(const int4v*)&idxq[((i < 6) ? i+2 : 7)*16];
    // cp/qw depth-1/2 (sequential, cache-friendly)
    int ni = (i < 7) ? i+1 : 7;
    f32x4 cpn = cp4l[ni];
    int n2 = (i < 6) ? i+2 : 7;
    f32x4 qvN = qwl4[n2*2];
    // idx for point i+3 (K/pos stream)
    int n3 = (i < 5) ? i+3 : 7;
    int iv3 = idxl[n3*16];

    // ---- H1 packed f16 -> f16 A-frags ----
    float np0 = ppA[0] - cpv[0], np1 = ppA[1] - cpv[1], np2 = ppA[2] - cpv[2];
    h2v np0h = {(_Float16)np0, (_Float16)np0};
    h2v np1h = {(_Float16)np1, (_Float16)np1};
    h2v np2h = {(_Float16)np2, (_Float16)np2};
    f16x8 h1f[2];
    #pragma unroll
    for (int ks = 0; ks < 2; ks++){
      union { f16x8 v; h2v p[4]; } hu;
      #pragma unroll
      for (int jj = 0; jj < 4; jj++){
        h2v a = cb[ks][jj];
        a = np0h*cw0[ks][jj] + a;
        a = np1h*cw1[ks][jj] + a;
        a = np2h*cw2[ks][jj] + a;
        hu.p[jj] = __builtin_elementwise_max(a, hz2);
      }
      h1f[ks] = hu.v;
    }

    // ---- weight-MLP hidden, TRANSPOSED (no LDS round-trip) ----
    f32x4 h2t = {qvA[0], qvA[1], qvA[2], qvA[3]};
    h2t = __builtin_amdgcn_mfma_f32_16x16x32_bf16(ww1f[0], kaA0, h2t, 0,0,0);
    h2t = __builtin_amdgcn_mfma_f32_16x16x32_bf16(ww1f[1], kaA1, h2t, 0,0,0);
    // relu+scale (per-row g), pack to f16 pairs, swap q0<->q1 via shfl
    h2v hp01 = mkh2(fmaxf(h2t[0]*wsr0 + wbr0, 0.f), fmaxf(h2t[1]*wsr1 + wbr1, 0.f));
    h2v hp23 = mkh2(fmaxf(h2t[2]*wsr2 + wbr2, 0.f), fmaxf(h2t[3]*wsr3 + wbr3, 0.f));
    union { h2v h; int i; } u01, u23, x01, x23;
    u01.h = hp01; u23.h = hp23;
    x01.i = __shfl_xor(u01.i, 16, 64);
    x23.i = __shfl_xor(u23.i, 16, 64);
    f16x8 ahf;
    {
      union { f16x8 v; h2v p[4]; } au;
      au.p[0] = u01.h; au.p[1] = u23.h; au.p[2] = x01.h; au.p[3] = x23.h;
      ahf = (q == 0) ? au.v : hz8;
    }

    // logits via f16 MFMA: wl[r] = logit[k=q*4+r][g=c]
    f32x4 wlv = {wb2_c, wb2_c, wb2_c, wb2_c};
    wlv = __builtin_amdgcn_mfma_f32_16x16x32_f16(ahf, w2B, wlv, 0,0,0);

    // softmax over 16 neighbors (logits O(1), no max-sub)
    float e0 = exp2f(wlv[0]*1.44269504f);
    float e1 = exp2f(wlv[1]*1.44269504f);
    float e2 = exp2f(wlv[2]*1.44269504f);
    float e3 = exp2f(wlv[3]*1.44269504f);
    float sm = e0+e1+e2+e3;
    sm += __shfl_xor(sm, 16, 64);
    sm += __shfl_xor(sm, 32, 64);
    float rn = 1.0f / sm;
    // weights to LDS f32: swt[g=c][k=q*4..q*4+3]
    if (c < 8){
      f32x4 ev = {e0*rn, e1*rn, e2*rn, e3*rn};
      *(f32x4*)&swt[c*20 + q*4] = ev;
    }

    // ---- P+V: MFMA with V in the accumulator, then weighted dot ----
    float ov[4];
    #pragma unroll
    for (int t = 0; t < 4; t++){
      f32x4 z = {bf2f((u16)vc[0][t]), bf2f((u16)vc[1][t]),
                 bf2f((u16)vc[2][t]), bf2f((u16)vc[3][t])};
      z = __builtin_amdgcn_mfma_f32_16x16x32_f16(h1f[0], pw2f[t][0], z, 0,0,0);
      z = __builtin_amdgcn_mfma_f32_16x16x32_f16(h1f[1], pw2f[t][1], z, 0,0,0);
      f32x4 wv = *(const f32x4*)&swt[(t*2+ch)*20 + q*4];
      ov[t] = z[0]*wv[0] + z[1]*wv[1] + z[2]*wv[2] + z[3]*wv[3];
    }
    #pragma unroll
    for (int t = 0; t < 4; t++){
      ov[t] += __shfl_xor(ov[t], 16, 64);
      ov[t] += __shfl_xor(ov[t], 32, 64);
    }
    float ovsel = ov[0];
    ovsel = (q==1) ? ov[1] : ovsel;
    ovsel = (q==2) ? ov[2] : ovsel;
    ovsel = (q==3) ? ov[3] : ovsel;

    s_tile[(w*8+i)*66 + l] = ovsel + pb2l;

    // rotate (named/static)
    kaA0 = kaB0; kaA1 = kaB1; ppA = ppB; qvA = qvB;
    kaB0 = kaN0; kaB1 = kaN1; ppB = ppN; qvB = qvN;
    cpv = cpn;
    iv2 = iv3;
    #pragma unroll
    for (int r = 0; r < 4; r++)
      #pragma unroll
      for (int t = 0; t < 4; t++)
        vc[r][t] = vn[r][t];
    iqA = iqB;
  }
  __syncthreads();

  // coalesced transposed store: out[b][o][m0+pt]
  int o0 = tid >> 5, pt = tid & 31;
  int m0 = pbase & (M_-1);
  long outb = ((long)b*64) * M_ + m0 + pt;
  #pragma unroll
  for (int ii = 0; ii < 8; ii++){
    int o = o0*8 + ii;
    out[outb + (long)o*M_] = s_tile[pt*66 + o];
  }
}

extern "C" void kernel_launch(void* const* d_in, const int* in_sizes, int n_in,
                              void* d_out, int out_size, void* d_ws, size_t ws_size,
                              hipStream_t stream) {
  const float* center_pos = (const float*)d_in[0];
  const float* center_fea = (const float*)d_in[1];
  const float* pos        = (const float*)d_in[2];
  const float* fea        = (const float*)d_in[3];
  const int*   idx        = (const int*)d_in[4];
  const float* Wq = (const float*)d_in[5];   const float* bq = (const float*)d_in[6];
  const float* Wk = (const float*)d_in[7];   const float* bk = (const float*)d_in[8];
  const float* Wv = (const float*)d_in[9];   const float* bv = (const float*)d_in[10];
  const float* cpe_w1 = (const float*)d_in[11]; const float* cpe_s = (const float*)d_in[12];
  const float* cpe_b  = (const float*)d_in[13]; const float* cpe_w2 = (const float*)d_in[14];
  const float* cpe_b2 = (const float*)d_in[15];
  const float* pe_w1 = (const float*)d_in[16]; const float* pe_s = (const float*)d_in[17];
  const float* pe_b  = (const float*)d_in[18]; const float* pe_w2 = (const float*)d_in[19];
  const float* pe_b2 = (const float*)d_in[20];
  const float* we_w1 = (const float*)d_in[21]; const float* we_s = (const float*)d_in[22];
  const float* we_b  = (const float*)d_in[23]; const float* we_w2 = (const float*)d_in[24];
  const float* we_b2 = (const float*)d_in[25];

  // ws: xk u16 | xv u16 | qw f32 | pos4 f32x4 | cp4 f32x4
  const size_t SZ = (size_t)B_*N_*64;
  u16* xk = (u16*)d_ws;
  u16* xv = xk + SZ;
  float* qwp = (float*)(xv + SZ);
  float* pos4p = qwp + (size_t)B_*M_*8;
  float* cp4p  = pos4p + (size_t)B_*N_*4;
  float* outp = (float*)d_out;

  hipLaunchKernelGGL(pre_kernel, dim3(512), dim3(256), 0, stream,
      center_pos, center_fea, pos, fea, Wq, bq, Wk, bk, Wv, bv,
      cpe_w1, cpe_s, cpe_b, cpe_w2, cpe_b2, we_w1,
      xk, xv, qwp, pos4p, cp4p);
  hipLaunchKernelGGL(attn_kernel, dim3(2048), dim3(256), 0, stream,
      cp4p, pos4p, idx, pe_w1, pe_s, pe_b, pe_w2, pe_b2,
      we_w1, we_s, we_b, we_w2, we_b2, xk, xv, qwp, outp);
}

// Round 10
// 198.044 us; speedup vs baseline: 1.0602x; 1.0244x over previous
//
#include <hip/hip_runtime.h>
#include <hip/hip_bf16.h>

typedef unsigned short u16;
typedef __attribute__((ext_vector_type(8))) __bf16 bf8v;
typedef __attribute__((ext_vector_type(8))) _Float16 f16x8;
typedef __attribute__((ext_vector_type(2))) _Float16 h2v;
typedef __attribute__((ext_vector_type(4))) float f32x4;
typedef __attribute__((ext_vector_type(4))) unsigned uint4v;
typedef __attribute__((ext_vector_type(4))) int int4v;

#define B_ 4
#define N_ 16384
#define M_ 16384
#define K_ 16
#define C_ 64
#define O_ 64
#define G_ 8

__device__ __forceinline__ float bf2f(u16 x){
  union { unsigned u; float f; } v; v.u = ((unsigned)x) << 16; return v.f;
}
__device__ __forceinline__ u16 f2bf(float f){
  union { float f; unsigned u; } v; v.f = f;
  unsigned u = v.u;
  return (u16)((u + 0x7FFFu + ((u >> 16) & 1u)) >> 16);
}
__device__ __forceinline__ u16 f2h(float f){
  union { _Float16 h; u16 u; } v; v.h = (_Float16)f; return v.u;
}
__device__ __forceinline__ h2v mkh2(float a, float b){
  h2v r = {(_Float16)a, (_Float16)b}; return r;
}

// ---------------------------------------------------------------------------
// pre_kernel (round-2/3 version, best measured residue): blocks [0,256) KV
// (+pos4 pack), [256,512) QC (+cp4 pack, inline Bw setup).  256 points/block.
// ---------------------------------------------------------------------------
__global__ __launch_bounds__(256) void pre_kernel(
    const float* __restrict__ center_pos, const float* __restrict__ center_fea,
    const float* __restrict__ pos, const float* __restrict__ fea,
    const float* __restrict__ Wq, const float* __restrict__ bq,
    const float* __restrict__ Wk, const float* __restrict__ bk,
    const float* __restrict__ Wv, const float* __restrict__ bv,
    const float* __restrict__ cpe_w1, const float* __restrict__ cpe_s, const float* __restrict__ cpe_b,
    const float* __restrict__ cpe_w2, const float* __restrict__ cpe_b2,
    const float* __restrict__ we_w1,
    u16* __restrict__ xk, u16* __restrict__ xv, float* __restrict__ qw,
    float* __restrict__ pos4, float* __restrict__ cp4)
{
  __shared__ u16 sWT[128*72];
  __shared__ u16 sA[64*72];
  __shared__ u16 sOut[64*136];
  __shared__ float sMisc[256];
  __shared__ float sCi[8];
  int tid = threadIdx.x;
  int l = tid & 63, w = tid >> 6, c = l & 15, q = l >> 4;
  int blk = blockIdx.x;

  if (blk < 256){
    int P0 = blk * 256; int b = P0 >> 14; int n00 = P0 & (N_-1);
    const float* fb = fea + (long)b*C_*N_;
    for (int e = tid; e < 8192; e += 256){
      int k = e >> 7, col = e & 127;
      float v = (col < 64) ? Wk[k*64 + col] : Wv[k*64 + (col-64)];
      sWT[col*72 + k] = f2bf(v);
    }
    if (tid < 128) sMisc[tid] = (tid < 64) ? bk[tid] : bv[tid-64];
    {
      long pg = (long)P0 + tid;
      f32x4 r = {pos[pg*3], pos[pg*3+1], pos[pg*3+2], 0.f};
      ((f32x4*)pos4)[pg] = r;
    }

    #pragma unroll 1
    for (int s = 0; s < 4; s++){
      int n0 = n00 + s*64;
      #pragma unroll
      for (int pp = 0; pp < 4; pp++){
        int k = pp*16 + (tid >> 4);
        int nf = (tid & 15)*4;
        f32x4 v = *(const f32x4*)&fb[(long)k*N_ + n0 + nf];
        sA[(nf+0)*72+k] = f2bf(v[0]); sA[(nf+1)*72+k] = f2bf(v[1]);
        sA[(nf+2)*72+k] = f2bf(v[2]); sA[(nf+3)*72+k] = f2bf(v[3]);
      }
      __syncthreads();

      bf8v af0 = *(const bf8v*)&sA[(w*16+c)*72 + q*8];
      bf8v af1 = *(const bf8v*)&sA[(w*16+c)*72 + 32 + q*8];
      f32x4 acc[8];
      #pragma unroll
      for (int t = 0; t < 8; t++){
        float bb = sMisc[16*t + c];
        f32x4 a_ = {bb, bb, bb, bb};
        bf8v b0 = *(const bf8v*)&sWT[(16*t + c)*72 + q*8];
        bf8v b1 = *(const bf8v*)&sWT[(16*t + c)*72 + 32 + q*8];
        a_ = __builtin_amdgcn_mfma_f32_16x16x32_bf16(af0, b0, a_, 0,0,0);
        a_ = __builtin_amdgcn_mfma_f32_16x16x32_bf16(af1, b1, a_, 0,0,0);
        acc[t] = a_;
      }
      #pragma unroll
      for (int t = 0; t < 8; t++)
        #pragma unroll
        for (int r = 0; r < 4; r++)
          sOut[(w*16 + q*4 + r)*136 + 16*t + c] = f2bf(acc[t][r]);
      __syncthreads();

      #pragma unroll
      for (int rep = 0; rep < 4; rep++){
        int chunk = rep*256 + tid;
        int pt = chunk >> 4, c8i = chunk & 15;
        uint4v val = *(const uint4v*)&sOut[pt*136 + c8i*8];
        int col8 = c8i*8;
        long row = (long)P0 + s*64 + pt;
        if (col8 < 64) *(uint4v*)(xk + row*64 + col8)      = val;
        else           *(uint4v*)(xv + row*64 + (col8-64)) = val;
      }
      __syncthreads();
    }
  } else {
    int P0 = (blk - 256) * 256; int b = P0 >> 14; int m00 = P0 & (M_-1);
    const float* cfb = center_fea + (long)b*C_*M_;
    float* sWe = (float*)sOut;
    float* sQ  = (float*)sOut;
    for (int e = tid; e < 512; e += 256) sWe[e] = we_w1[e];
    if (tid < 64){
      float sc = cpe_s[tid];
      sMisc[tid]     = cpe_w1[tid]*sc;
      sMisc[64+tid]  = cpe_w1[64+tid]*sc;
      sMisc[128+tid] = cpe_w1[128+tid]*sc;
      sMisc[192+tid] = cpe_b[tid];
    }
    {
      long pg = (long)P0 + tid;
      f32x4 r = {center_pos[pg*3], center_pos[pg*3+1], center_pos[pg*3+2], 0.f};
      ((f32x4*)cp4)[pg] = r;
    }
    __syncthreads();
    {
      int k = tid >> 1, g0 = (tid & 1)*4;
      const float* brow = (k < 64) ? (cpe_w2 + k*64) : (Wq + (k-64)*64);
      float sgn = (k < 64) ? 1.f : -1.f;
      float aw[4] = {0.f,0.f,0.f,0.f};
      for (int o = 0; o < 64; o++){
        float bo = brow[o]*sgn;
        #pragma unroll
        for (int gg=0; gg<4; gg++) aw[gg] += bo * sWe[o*8 + g0+gg];
      }
      #pragma unroll
      for (int gg=0; gg<4; gg++) sWT[(g0+gg)*136 + k] = f2bf(aw[gg]);
    }
    for (int e = tid; e < 2176; e += 256){
      int r = e / 136, cc = e % 136;
      if (r >= 8 || cc >= 128) sWT[e] = 0;
    }
    if (tid < 8){
      float s = 0.f;
      for (int o = 0; o < 64; o++) s += (cpe_b2[o] - bq[o]) * sWe[o*8 + tid];
      sCi[tid] = s;
    }
    __syncthreads();

    #pragma unroll 1
    for (int s = 0; s < 4; s++){
      int m0 = m00 + s*64;
      #pragma unroll
      for (int pp = 0; pp < 4; pp++){
        int k = pp*16 + (tid >> 4);
        int nf = (tid & 15)*4;
        f32x4 v = *(const f32x4*)&cfb[(long)k*M_ + m0 + nf];
        sA[(nf+0)*72+k] = f2bf(v[0]); sA[(nf+1)*72+k] = f2bf(v[1]);
        sA[(nf+2)*72+k] = f2bf(v[2]); sA[(nf+3)*72+k] = f2bf(v[3]);
      }
      long c3 = (long)(P0 + s*64 + w*16 + c)*3;
      float cp0 = center_pos[c3], cp1 = center_pos[c3+1], cp2 = center_pos[c3+2];
      __syncthreads();

      bf8v ah[2];
      #pragma unroll
      for (int ks = 0; ks < 2; ks++){
        union { bf8v v; u16 sv[8]; } ua;
        #pragma unroll
        for (int j = 0; j < 8; j++){
          int h = ks*32 + q*8 + j;
          float hv = cp0*sMisc[h] + cp1*sMisc[64+h] + cp2*sMisc[128+h] + sMisc[192+h];
          ua.sv[j] = f2bf(fmaxf(hv, 0.f));
        }
        ah[ks] = ua.v;
      }
      bf8v acf0 = *(const bf8v*)&sA[(w*16+c)*72 + q*8];
      bf8v acf1 = *(const bf8v*)&sA[(w*16+c)*72 + 32 + q*8];

      float ci = (c < 8) ? sCi[c] : 0.f;
      f32x4 aq = {ci, ci, ci, ci};
      {
        bf8v b0 = *(const bf8v*)&sWT[c*136 + q*8];
        bf8v b1 = *(const bf8v*)&sWT[c*136 + 32 + q*8];
        bf8v b2 = *(const bf8v*)&sWT[c*136 + 64 + q*8];
        bf8v b3 = *(const bf8v*)&sWT[c*136 + 96 + q*8];
        aq = __builtin_amdgcn_mfma_f32_16x16x32_bf16(ah[0], b0, aq, 0,0,0);
        aq = __builtin_amdgcn_mfma_f32_16x16x32_bf16(ah[1], b1, aq, 0,0,0);
        aq = __builtin_amdgcn_mfma_f32_16x16x32_bf16(acf0,  b2, aq, 0,0,0);
        aq = __builtin_amdgcn_mfma_f32_16x16x32_bf16(acf1,  b3, aq, 0,0,0);
      }
      __syncthreads();
      if (c < 8){
        #pragma unroll
        for (int r = 0; r < 4; r++) sQ[(w*16 + q*4 + r)*8 + c] = aq[r];
      }
      __syncthreads();
      for (int e = tid; e < 512; e += 256)
        qw[(long)(P0 + s*64)*8 + e] = sQ[e];
      __syncthreads();
    }
  }
}

// ---------------------------------------------------------------------------
// attn_kernel v10: v9 (transposed hidden MFMA, V-in-accumulator, XCD swizzle,
// depth-2 pipeline) + DEFERRED TAIL:
//  - output cross-q reduce moved to epilogue: lane writes raw f32x4 partials
//    to s_part (fire-and-forget); deletes 8 shfls + select per iteration
//  - softmax normalization deferred: swt holds UNNORMALIZED e's; rn=1/sm
//    stored per (point,g) in s_rn and applied in the epilogue -> the sm
//    reduce shfls leave the critical path
// ---------------------------------------------------------------------------
__global__ __launch_bounds__(256) void attn_kernel(
    const float* __restrict__ cp4, const float* __restrict__ pos4,
    const int* __restrict__ idx,
    const float* __restrict__ pe_w1, const float* __restrict__ pe_s, const float* __restrict__ pe_b,
    const float* __restrict__ pe_w2, const float* __restrict__ pe_b2,
    const float* __restrict__ we_w1, const float* __restrict__ we_s, const float* __restrict__ we_b,
    const float* __restrict__ we_w2, const float* __restrict__ we_b2,
    const u16* __restrict__ xk, const u16* __restrict__ xv, const float* __restrict__ qw,
    float* __restrict__ out)
{
  int tid = threadIdx.x;
  __shared__ float s_w1f[192], s_pb[64], s_pb2[64], s_ww2[64];
  __shared__ float s_ws8[8], s_wb8[8], s_wb28[8];
  // dynb layout: [0,3072) swt (4 waves x 768) | [3072,36352) s_part
  // (32 points x 1040 B) | [36352,37376) s_rn (32x8 f32).
  // Staging (11520 B at base) aliases swt+s_part head; consumed pre-loop.
  __shared__ f32x4 s_dyn4[2336];

  char* dynb = (char*)s_dyn4;

  if (tid < 64){
    float sc = pe_s[tid];
    s_w1f[tid]     = pe_w1[tid]*sc;
    s_w1f[64+tid]  = pe_w1[64+tid]*sc;
    s_w1f[128+tid] = pe_w1[128+tid]*sc;
    s_pb[tid]  = pe_b[tid];
    s_pb2[tid] = pe_b2[tid];
    s_ww2[tid] = we_w2[tid];
  }
  if (tid >= 64 && tid < 72){
    int g = tid-64;
    s_ws8[g]=we_s[g]; s_wb8[g]=we_b[g]; s_wb28[g]=we_b2[g];
  }
  // stage pe_w2^T [col o][k] stride 72, f16
  u16* stg = (u16*)dynb;
  #pragma unroll
  for (int pp = 0; pp < 4; pp++){
    int row = pp*16 + (tid >> 4);
    int colf = (tid & 15)*4;
    f32x4 v = *(const f32x4*)&pe_w2[row*64 + colf];
    stg[(colf+0)*72+row] = f2h(v[0]); stg[(colf+1)*72+row] = f2h(v[1]);
    stg[(colf+2)*72+row] = f2h(v[2]); stg[(colf+3)*72+row] = f2h(v[3]);
  }
  // stage we_w1^T rows 0..7 (bf16), zero rows 8..15
  u16* stg2 = (u16*)(dynb + 9216);
  for (int e = tid; e < 512; e += 256){
    int k = e >> 3, cc = e & 7;
    stg2[cc*72 + k] = f2bf(we_w1[e]);
  }
  for (int e = tid; e < 576; e += 256) stg2[576 + e] = 0;
  __syncthreads();

  int w = tid >> 6, l = tid & 63, c = l & 15, q = l >> 4, c8 = c & 7;

  f16x8 pw2f[4][2];
  bf8v ww1f[2];
  f16x8 w2B, hz8;
  #pragma unroll
  for (int t = 0; t < 4; t++){
    pw2f[t][0] = *(const f16x8*)&stg[(t*16+c)*72 + q*8];
    pw2f[t][1] = *(const f16x8*)&stg[(t*16+c)*72 + 32 + q*8];
  }
  ww1f[0] = *(const bf8v*)&stg2[c*72 + q*8];
  ww1f[1] = *(const bf8v*)&stg2[c*72 + 32 + q*8];
  {
    union { f16x8 v; u16 s[8]; } uu;
    #pragma unroll
    for (int j = 0; j < 8; j++)
      uu.s[j] = (q == 0 && c < 8) ? f2h(s_ww2[j*8 + c]) : (u16)0;
    w2B = uu.v;
    #pragma unroll
    for (int j = 0; j < 8; j++) uu.s[j] = 0;
    hz8 = uu.v;
  }
  // register-resident packed-f16 H1 coefficients (16 o-values per lane)
  h2v cw0[2][4], cw1[2][4], cw2[2][4], cb[2][4];
  #pragma unroll
  for (int ks = 0; ks < 2; ks++)
    #pragma unroll
    for (int jj = 0; jj < 4; jj++){
      int o = ks*32 + q*8 + jj*2;
      cw0[ks][jj] = mkh2(s_w1f[o],     s_w1f[o+1]);
      cw1[ks][jj] = mkh2(s_w1f[64+o],  s_w1f[65+o]);
      cw2[ks][jj] = mkh2(s_w1f[128+o], s_w1f[129+o]);
      cb [ks][jj] = mkh2(s_pb[o],      s_pb[o+1]);
    }
  // relu scale/bias for TRANSPOSED hidden rows g=q*4+r (zero for q>=2)
  int qok = (q < 2);
  int gq = (q & 1)*4;
  float wsr0 = qok ? s_ws8[gq+0] : 0.f, wbr0 = qok ? s_wb8[gq+0] : 0.f;
  float wsr1 = qok ? s_ws8[gq+1] : 0.f, wbr1 = qok ? s_wb8[gq+1] : 0.f;
  float wsr2 = qok ? s_ws8[gq+2] : 0.f, wbr2 = qok ? s_wb8[gq+2] : 0.f;
  float wsr3 = qok ? s_ws8[gq+3] : 0.f, wbr3 = qok ? s_wb8[gq+3] : 0.f;
  float wb2_c = s_wb28[c8];
  h2v hz2 = {(_Float16)0.f, (_Float16)0.f};
  __syncthreads();   // stage region -> per-wave swt / s_part

  // per-wave: swt f32 8x20 (640 B in 768-B slot); s_part/s_rn shared
  float* swt = (float*)(dynb + w*768);
  char*  spart = dynb + 3072;
  float* srn = (float*)(dynb + 36352);

  // XCD-aware swizzle (2048 blocks % 8 == 0 -> bijective)
  int blk = blockIdx.x;
  int pbase = (((blk & 7) << 8) | (blk >> 3)) * 32;
  int b = pbase >> 14;
  const u16* xkb = xk + (long)b * N_ * 64;
  const u16* xvb = xv + (long)b * N_ * 64;
  const f32x4* pos4b = ((const f32x4*)pos4) + (long)b * N_;
  int ch = c >> 3;

  // scalar streams: base + immediate offsets
  int pb0 = pbase + w*8;
  const int*   idxl = idx + (long)pb0*16 + c;
  const int*   idxq = idx + (long)pb0*16 + q*4;
  const f32x4* qwl4 = ((const f32x4*)(qw + (long)pb0*8)) + (q & 1);
  const f32x4* cp4l = ((const f32x4*)cp4) + pb0;

  // ---- prologue ----
  int iv0 = idxl[0];
  int ivt = idxl[16];
  int iv2 = idxl[32];
  f32x4 qvA = qwl4[0];
  f32x4 qvB = qwl4[2];
  f32x4 cpv = cp4l[0];
  // K/pos point 0 -> set A
  f32x4 ppA = pos4b[iv0];
  const u16* krA = xkb + (size_t)iv0*64;
  bf8v kaA0 = *(const bf8v*)(krA + q*8);
  bf8v kaA1 = *(const bf8v*)(krA + 32 + q*8);
  // K/pos point 1 -> set B
  f32x4 ppB = pos4b[ivt];
  const u16* krB = xkb + (size_t)ivt*64;
  bf8v kaB0 = *(const bf8v*)(krB + q*8);
  bf8v kaB1 = *(const bf8v*)(krB + 32 + q*8);
  // V in acc layout: point 0 now, idx quad for point 1 resolved
  int4v iq0 = *(const int4v*)&idxq[0];
  int4v iqA = *(const int4v*)&idxq[16];
  unsigned vc[4][4];
  #pragma unroll
  for (int r = 0; r < 4; r++){
    const u16* vrow = xvb + (size_t)iq0[r]*64 + c;
    #pragma unroll
    for (int t = 0; t < 4; t++)
      vc[r][t] = vrow[t*16];
  }

  #pragma unroll 1
  for (int i = 0; i < 8; i++){
    // ---- K/pos gathers for point i+2 (address iv2 resolved 2 iters ago) ----
    f32x4 ppN = pos4b[iv2];
    const u16* krN = xkb + (size_t)iv2*64;
    bf8v kaN0 = *(const bf8v*)(krN + q*8);
    bf8v kaN1 = *(const bf8v*)(krN + 32 + q*8);
    // ---- V gathers for point i+1 in acc layout (iqA resolved last iter) ----
    unsigned vn[4][4];
    #pragma unroll
    for (int r = 0; r < 4; r++){
      const u16* vrow = xvb + (size_t)iqA[r]*64 + c;
      #pragma unroll
      for (int t = 0; t < 4; t++)
        vn[r][t] = vrow[t*16];
    }
    int4v iqB = *(const int4v*)&idxq[((i < 6) ? i+2 : 7)*16];
    // cp/qw depth-1/2 (sequential, cache-friendly)
    int ni = (i < 7) ? i+1 : 7;
    f32x4 cpn = cp4l[ni];
    int n2 = (i < 6) ? i+2 : 7;
    f32x4 qvN = qwl4[n2*2];
    // idx for point i+3 (K/pos stream)
    int n3 = (i < 5) ? i+3 : 7;
    int iv3 = idxl[n3*16];

    // ---- H1 packed f16 -> f16 A-frags ----
    float np0 = ppA[0] - cpv[0], np1 = ppA[1] - cpv[1], np2 = ppA[2] - cpv[2];
    h2v np0h = {(_Float16)np0, (_Float16)np0};
    h2v np1h = {(_Float16)np1, (_Float16)np1};
    h2v np2h = {(_Float16)np2, (_Float16)np2};
    f16x8 h1f[2];
    #pragma unroll
    for (int ks = 0; ks < 2; ks++){
      union { f16x8 v; h2v p[4]; } hu;
      #pragma unroll
      for (int jj = 0; jj < 4; jj++){
        h2v a = cb[ks][jj];
        a = np0h*cw0[ks][jj] + a;
        a = np1h*cw1[ks][jj] + a;
        a = np2h*cw2[ks][jj] + a;
        hu.p[jj] = __builtin_elementwise_max(a, hz2);
      }
      h1f[ks] = hu.v;
    }

    // ---- weight-MLP hidden, TRANSPOSED (no LDS round-trip) ----
    f32x4 h2t = {qvA[0], qvA[1], qvA[2], qvA[3]};
    h2t = __builtin_amdgcn_mfma_f32_16x16x32_bf16(ww1f[0], kaA0, h2t, 0,0,0);
    h2t = __builtin_amdgcn_mfma_f32_16x16x32_bf16(ww1f[1], kaA1, h2t, 0,0,0);
    // relu+scale (per-row g), pack to f16 pairs, swap q0<->q1 via shfl
    h2v hp01 = mkh2(fmaxf(h2t[0]*wsr0 + wbr0, 0.f), fmaxf(h2t[1]*wsr1 + wbr1, 0.f));
    h2v hp23 = mkh2(fmaxf(h2t[2]*wsr2 + wbr2, 0.f), fmaxf(h2t[3]*wsr3 + wbr3, 0.f));
    union { h2v h; int i; } u01, u23, x01, x23;
    u01.h = hp01; u23.h = hp23;
    x01.i = __shfl_xor(u01.i, 16, 64);
    x23.i = __shfl_xor(u23.i, 16, 64);
    f16x8 ahf;
    {
      union { f16x8 v; h2v p[4]; } au;
      au.p[0] = u01.h; au.p[1] = u23.h; au.p[2] = x01.h; au.p[3] = x23.h;
      ahf = (q == 0) ? au.v : hz8;
    }

    // logits via f16 MFMA: wl[r] = logit[k=q*4+r][g=c]
    f32x4 wlv = {wb2_c, wb2_c, wb2_c, wb2_c};
    wlv = __builtin_amdgcn_mfma_f32_16x16x32_f16(ahf, w2B, wlv, 0,0,0);

    // exp; UNNORMALIZED weights straight to swt (norm deferred to epilogue)
    float e0 = exp2f(wlv[0]*1.44269504f);
    float e1 = exp2f(wlv[1]*1.44269504f);
    float e2 = exp2f(wlv[2]*1.44269504f);
    float e3 = exp2f(wlv[3]*1.44269504f);
    if (c < 8){
      f32x4 ev = {e0, e1, e2, e3};
      *(f32x4*)&swt[c*20 + q*4] = ev;
    }
    // sm reduce + rcp off the critical path (consumed only in epilogue)
    float sm = e0+e1+e2+e3;
    sm += __shfl_xor(sm, 16, 64);
    sm += __shfl_xor(sm, 32, 64);
    float rn = 1.0f / sm;
    if (q == 0 && c < 8) srn[(w*8+i)*8 + c] = rn;

    // ---- P+V: MFMA with V in the accumulator, then raw-weighted dot ----
    float ov[4];
    #pragma unroll
    for (int t = 0; t < 4; t++){
      f32x4 z = {bf2f((u16)vc[0][t]), bf2f((u16)vc[1][t]),
                 bf2f((u16)vc[2][t]), bf2f((u16)vc[3][t])};
      z = __builtin_amdgcn_mfma_f32_16x16x32_f16(h1f[0], pw2f[t][0], z, 0,0,0);
      z = __builtin_amdgcn_mfma_f32_16x16x32_f16(h1f[1], pw2f[t][1], z, 0,0,0);
      f32x4 wv = *(const f32x4*)&swt[(t*2+ch)*20 + q*4];
      ov[t] = z[0]*wv[0] + z[1]*wv[1] + z[2]*wv[2] + z[3]*wv[3];
    }
    // q-local partials to s_part; cross-q reduce deferred to epilogue
    {
      f32x4 pv = {ov[0], ov[1], ov[2], ov[3]};
      *(f32x4*)(spart + (w*8+i)*1040 + c*64 + q*16) = pv;
    }

    // rotate (named/static)
    kaA0 = kaB0; kaA1 = kaB1; ppA = ppB; qvA = qvB;
    kaB0 = kaN0; kaB1 = kaN1; ppB = ppN; qvB = qvN;
    cpv = cpn;
    iv2 = iv3;
    #pragma unroll
    for (int r = 0; r < 4; r++)
      #pragma unroll
      for (int t = 0; t < 4; t++)
        vc[r][t] = vn[r][t];
    iqA = iqB;
  }
  __syncthreads();

  // epilogue: cross-q reduce + deferred softmax normalization + bias
  {
    int pt = tid & 31, cc = tid >> 5;   // cc 0..7
    const char* partp = spart + pt*1040;
    int m0 = pbase & (M_-1);
    long outb = ((long)b*64) * M_ + m0 + pt;
    #pragma unroll
    for (int half = 0; half < 2; half++){
      int c_ = cc + half*8;
      const f32x4* pp4 = (const f32x4*)(partp + c_*64);
      f32x4 sum = pp4[0] + pp4[1] + pp4[2] + pp4[3];
      #pragma unroll
      for (int t = 0; t < 4; t++){
        int o = t*16 + c_;
        float rnv = srn[pt*8 + t*2 + half];
        out[outb + (long)o*M_] = sum[t]*rnv + s_pb2[o];
      }
    }
  }
}

extern "C" void kernel_launch(void* const* d_in, const int* in_sizes, int n_in,
                              void* d_out, int out_size, void* d_ws, size_t ws_size,
                              hipStream_t stream) {
  const float* center_pos = (const float*)d_in[0];
  const float* center_fea = (const float*)d_in[1];
  const float* pos        = (const float*)d_in[2];
  const float* fea        = (const float*)d_in[3];
  const int*   idx        = (const int*)d_in[4];
  const float* Wq = (const float*)d_in[5];   const float* bq = (const float*)d_in[6];
  const float* Wk = (const float*)d_in[7];   const float* bk = (const float*)d_in[8];
  const float* Wv = (const float*)d_in[9];   const float* bv = (const float*)d_in[10];
  const float* cpe_w1 = (const float*)d_in[11]; const float* cpe_s = (const float*)d_in[12];
  const float* cpe_b  = (const float*)d_in[13]; const float* cpe_w2 = (const float*)d_in[14];
  const float* cpe_b2 = (const float*)d_in[15];
  const float* pe_w1 = (const float*)d_in[16]; const float* pe_s = (const float*)d_in[17];
  const float* pe_b  = (const float*)d_in[18]; const float* pe_w2 = (const float*)d_in[19];
  const float* pe_b2 = (const float*)d_in[20];
  const float* we_w1 = (const float*)d_in[21]; const float* we_s = (const float*)d_in[22];
  const float* we_b  = (const float*)d_in[23]; const float* we_w2 = (const float*)d_in[24];
  const float* we_b2 = (const float*)d_in[25];

  // ws: xk u16 | xv u16 | qw f32 | pos4 f32x4 | cp4 f32x4
  const size_t SZ = (size_t)B_*N_*64;
  u16* xk = (u16*)d_ws;
  u16* xv = xk + SZ;
  float* qwp = (float*)(xv + SZ);
  float* pos4p = qwp + (size_t)B_*M_*8;
  float* cp4p  = pos4p + (size_t)B_*N_*4;
  float* outp = (float*)d_out;

  hipLaunchKernelGGL(pre_kernel, dim3(512), dim3(256), 0, stream,
      center_pos, center_fea, pos, fea, Wq, bq, Wk, bk, Wv, bv,
      cpe_w1, cpe_s, cpe_b, cpe_w2, cpe_b2, we_w1,
      xk, xv, qwp, pos4p, cp4p);
  hipLaunchKernelGGL(attn_kernel, dim3(2048), dim3(256), 0, stream,
      cp4p, pos4p, idx, pe_w1, pe_s, pe_b, pe_w2, pe_b2,
      we_w1, we_s, we_b, we_w2, we_b2, xk, xv, qwp, outp);
}